// Round 3
// baseline (2640.681 us; speedup 1.0000x reference)
//
#include <hip/hip_runtime.h>
#include <math.h>

#define NN 50000
#define F 128

// ---------------- small utility kernels ----------------
__global__ void zero_int_kernel(int* __restrict__ p, int n) {
    int i = blockIdx.x * blockDim.x + threadIdx.x;
    if (i < n) p[i] = 0;
}

// count in-degree (excl self loop) into cnt
__global__ void deg_count_kernel(const int* __restrict__ dst, int* __restrict__ cnt, int E) {
    int i = blockIdx.x * blockDim.x + threadIdx.x;
    if (i < E) atomicAdd(&cnt[dst[i]], 1);
}

// dinv = rsqrt(cnt + 1)   (self loop adds 1)
__global__ void dinv_kernel(const int* __restrict__ cnt, float* __restrict__ dinv, int n) {
    int i = blockIdx.x * blockDim.x + threadIdx.x;
    if (i < n) dinv[i] = rsqrtf((float)(cnt[i] + 1));
}

// ---------------- 3-phase exclusive scan over cnt -> rowptr ----------------
// pass 1: each block scans 1024 elems (256 thr x int4), writes local-exclusive
// scan into rowptr and its block total into bsums. cnt must be zero-padded to
// a multiple of 1024.
__global__ __launch_bounds__(256) void scan1_kernel(const int* __restrict__ cnt,
                                                    int* __restrict__ rowptr,
                                                    int* __restrict__ bsums) {
    __shared__ int wsum[4];
    int tid = threadIdx.x;
    int lane = tid & 63;
    int wv = tid >> 6;
    int i0 = blockIdx.x * 1024 + tid * 4;
    int4 v = *(const int4*)&cnt[i0];
    int s = v.x + v.y + v.z + v.w;
    int inc = s;
#pragma unroll
    for (int off = 1; off < 64; off <<= 1) {
        int t = __shfl_up(inc, off, 64);
        if (lane >= off) inc += t;
    }
    if (lane == 63) wsum[wv] = inc;
    __syncthreads();
    int woff = 0;
#pragma unroll
    for (int w2 = 0; w2 < 4; ++w2)
        if (w2 < wv) woff += wsum[w2];
    int base = woff + inc - s;  // thread-exclusive
    int4 o;
    o.x = base;
    o.y = base + v.x;
    o.z = o.y + v.y;
    o.w = o.z + v.z;
    *(int4*)&rowptr[i0] = o;
    if (tid == 255) bsums[blockIdx.x] = woff + inc;
}

// pass 2: exclusive scan of block sums (nb <= 64), one wave
__global__ void scan2_kernel(int* __restrict__ bsums, int nb) {
    int lane = threadIdx.x;
    int v = (lane < nb) ? bsums[lane] : 0;
    int inc = v;
#pragma unroll
    for (int off = 1; off < 64; off <<= 1) {
        int t = __shfl_up(inc, off, 64);
        if (lane >= off) inc += t;
    }
    if (lane < nb) bsums[lane] = inc - v;
}

// pass 3: add block offsets; also produce cursor copy and rowptr[n]=E
__global__ void scan3_kernel(int* __restrict__ rowptr, const int* __restrict__ bsums,
                             int* __restrict__ cursor, int n, int E) {
    int i = blockIdx.x * blockDim.x + threadIdx.x;
    if (i < n) {
        int val = rowptr[i] + bsums[i >> 10];
        rowptr[i] = val;
        cursor[i] = val;
    }
    if (i == 0) rowptr[n] = E;
}

// fill CSR: csr_src[pos] = src[e] bucketed by dst
__global__ void fill_kernel(const int* __restrict__ src, const int* __restrict__ dst,
                            int* __restrict__ cursor, int* __restrict__ csr_src, int E) {
    int i = blockIdx.x * blockDim.x + threadIdx.x;
    if (i < E) {
        int d = dst[i];
        int pos = atomicAdd(&cursor[d], 1);
        csr_src[pos] = src[i];
    }
}

// ---------------- GEMM: g = (x @ W) * dinv[row] ----------------
// 512 threads, 128 rows/block. W fully staged in LDS (64 KB).
// Thread = (colgrp 0..31)*(4 cols) x (rowthread 0..15)*(8 rows). 32 accs.
__global__ __launch_bounds__(512, 4) void gemm_kernel(
    const float* __restrict__ x, const float* __restrict__ W,
    const float* __restrict__ dinv, float* __restrict__ g, int n) {
    __shared__ float Wl[F * F];  // 64 KB
    int tid = threadIdx.x;
    {
        const float4* Wv = (const float4*)W;
        float4* Wlv = (float4*)Wl;
#pragma unroll
        for (int i = 0; i < 8; ++i) Wlv[tid + 512 * i] = Wv[tid + 512 * i];
    }
    __syncthreads();

    int c = (tid & 31) * 4;   // col base
    int rt = tid >> 5;        // 0..15
    int r0 = blockIdx.x * 128 + rt * 8;

    const float* xr[8];
#pragma unroll
    for (int i = 0; i < 8; ++i) xr[i] = x + (size_t)min(r0 + i, n - 1) * F;

    float4 acc[8] = {};

#pragma unroll
    for (int ch = 0; ch < 32; ++ch) {  // k chunks of 4
        int kc = ch * 4;
        float4 xv[8];
#pragma unroll
        for (int i = 0; i < 8; ++i) xv[i] = *(const float4*)(xr[i] + kc);
#pragma unroll
        for (int kk = 0; kk < 4; ++kk) {
            float4 w = *(const float4*)&Wl[(kc + kk) * F + c];
#pragma unroll
            for (int i = 0; i < 8; ++i) {
                float xs = ((const float*)&xv[i])[kk];
                acc[i].x += xs * w.x;
                acc[i].y += xs * w.y;
                acc[i].z += xs * w.z;
                acc[i].w += xs * w.w;
            }
        }
    }

#pragma unroll
    for (int i = 0; i < 8; ++i) {
        int rr = r0 + i;
        if (rr < n) {
            float di = dinv[rr];
            float4 o;
            o.x = acc[i].x * di;
            o.y = acc[i].y * di;
            o.z = acc[i].z * di;
            o.w = acc[i].w * di;
            *(float4*)&g[(size_t)rr * F + c] = o;
        }
    }
}

// ---------------- aggregate: out[d] = [relu](dinv[d]*(sum_{s in N(d)} g[s] + g[d]) + b) ----------------
template <bool RELU>
__global__ __launch_bounds__(256) void aggregate_kernel(
    const int* __restrict__ rowptr, const int* __restrict__ csr_src,
    const float* __restrict__ dinv, const float* __restrict__ g,
    const float* __restrict__ bias, float* __restrict__ out, int n) {
    int lane = threadIdx.x & 63;
    int d = (blockIdx.x * blockDim.x + threadIdx.x) >> 6;
    if (d >= n) return;
    int c = lane * 2;

    float2 acc = *(const float2*)&g[(size_t)d * F + c];  // self loop

    int e = rowptr[d];
    int end = rowptr[d + 1];
    for (; e + 4 <= end; e += 4) {
        int s0 = csr_src[e];
        int s1 = csr_src[e + 1];
        int s2 = csr_src[e + 2];
        int s3 = csr_src[e + 3];
        float2 v0 = *(const float2*)&g[(size_t)s0 * F + c];
        float2 v1 = *(const float2*)&g[(size_t)s1 * F + c];
        float2 v2 = *(const float2*)&g[(size_t)s2 * F + c];
        float2 v3 = *(const float2*)&g[(size_t)s3 * F + c];
        acc.x += v0.x + v1.x + v2.x + v3.x;
        acc.y += v0.y + v1.y + v2.y + v3.y;
    }
    for (; e < end; ++e) {
        int s = csr_src[e];
        float2 v = *(const float2*)&g[(size_t)s * F + c];
        acc.x += v.x;
        acc.y += v.y;
    }

    float di = dinv[d];
    float2 b = *(const float2*)&bias[c];
    float2 r;
    r.x = di * acc.x + b.x;
    r.y = di * acc.y + b.y;
    if (RELU) {
        r.x = fmaxf(r.x, 0.0f);
        r.y = fmaxf(r.y, 0.0f);
    }
    *(float2*)&out[(size_t)d * F + c] = r;
}

// ---------------- decode: out = sigmoid(dot(z[ls], z[ld])) ----------------
__global__ __launch_bounds__(256) void decode_kernel(
    const int* __restrict__ ls, const int* __restrict__ ld,
    const float* __restrict__ z, float* __restrict__ out, int EL) {
    int lane = threadIdx.x & 63;
    int w = (blockIdx.x * blockDim.x + threadIdx.x) >> 6;
    if (w >= EL) return;
    int a = ls[w];
    int b = ld[w];
    float2 va = *(const float2*)&z[(size_t)a * F + lane * 2];
    float2 vb = *(const float2*)&z[(size_t)b * F + lane * 2];
    float s = va.x * vb.x + va.y * vb.y;
#pragma unroll
    for (int off = 32; off; off >>= 1) s += __shfl_xor(s, off, 64);
    if (lane == 0) out[w] = 1.0f / (1.0f + expf(-s));
}

extern "C" void kernel_launch(void* const* d_in, const int* in_sizes, int n_in,
                              void* d_out, int out_size, void* d_ws, size_t ws_size,
                              hipStream_t stream) {
    const float* x = (const float*)d_in[0];
    const int* ei = (const int*)d_in[1];
    const int* eli = (const int*)d_in[2];
    const float* W1 = (const float*)d_in[3];
    const float* b1 = (const float*)d_in[4];
    const float* W2 = (const float*)d_in[5];
    const float* b2 = (const float*)d_in[6];
    float* out = (float*)d_out;

    int E = in_sizes[1] / 2;
    int EL = in_sizes[2] / 2;
    const int* src = ei;
    const int* dst = ei + E;
    const int* ls = eli;
    const int* ld = eli + EL;
    int n = in_sizes[0] / F;  // 50000

    int nb_scan = (n + 1023) / 1024;          // 49
    int npad = nb_scan * 1024;                // 50176

    char* ws = (char*)d_ws;
    float* dinv   = (float*)(ws);                        // [0,1MB)
    int*   rowptr = (int*)(ws + (1u << 20));             // [1MB,2MB): n+1 (padded writes ok)
    int*   cnt    = (int*)(ws + (2u << 20));             // 256KB
    int*   cursor = (int*)(ws + (2u << 20) + 262144u);   // 256KB
    int*   bsums  = (int*)(ws + (2u << 20) + 524288u);   // small
    int*   csr    = (int*)(ws + (3u << 20));             // [3MB,6.2MB): E ints
    float* bufA   = (float*)(ws + (8u << 20));           // g, 25.6MB
    float* bufB   = (float*)(ws + (8u << 20) + 26214400u);  // z1/z2, 25.6MB

    const int BS = 256;
    int nb_pad   = (npad + BS - 1) / BS;
    int nb_nodes = (n + BS - 1) / BS;
    int nb_edges = (E + BS - 1) / BS;
    int gemm_blocks = (n + 127) / 128;
    int agg_blocks = (n + 3) / 4;
    int dec_blocks = (EL + 3) / 4;

    // ---- CSR build ----
    zero_int_kernel<<<nb_pad, BS, 0, stream>>>(cnt, npad);
    deg_count_kernel<<<nb_edges, BS, 0, stream>>>(dst, cnt, E);
    dinv_kernel<<<nb_nodes, BS, 0, stream>>>(cnt, dinv, n);
    scan1_kernel<<<nb_scan, BS, 0, stream>>>(cnt, rowptr, bsums);
    scan2_kernel<<<1, 64, 0, stream>>>(bsums, nb_scan);
    scan3_kernel<<<nb_pad, BS, 0, stream>>>(rowptr, bsums, cursor, n, E);
    fill_kernel<<<nb_edges, BS, 0, stream>>>(src, dst, cursor, csr, E);

    // ---- layer 1 ----
    gemm_kernel<<<gemm_blocks, 512, 0, stream>>>(x, W1, dinv, bufA, n);
    aggregate_kernel<true><<<agg_blocks, BS, 0, stream>>>(rowptr, csr, dinv, bufA, b1, bufB, n);

    // ---- layer 2 ----
    gemm_kernel<<<gemm_blocks, 512, 0, stream>>>(bufB, W2, dinv, bufA, n);
    aggregate_kernel<false><<<agg_blocks, BS, 0, stream>>>(rowptr, csr, dinv, bufA, b2, bufB, n);

    // ---- decode ----
    decode_kernel<<<dec_blocks, BS, 0, stream>>>(ls, ld, bufB, out, EL);
}

// Round 4
// 1941.226 us; speedup vs baseline: 1.3603x; 1.3603x over previous
//
#include <hip/hip_runtime.h>
#include <math.h>

#define NN 50000
#define F 128

// ---------------- small utility kernels ----------------
__global__ void zero_int_kernel(int* __restrict__ p, int n) {
    int i = blockIdx.x * blockDim.x + threadIdx.x;
    if (i < n) p[i] = 0;
}

// count in-degree (excl self loop) into cnt
__global__ void deg_count_kernel(const int* __restrict__ dst, int* __restrict__ cnt, int E) {
    int i = blockIdx.x * blockDim.x + threadIdx.x;
    if (i < E) atomicAdd(&cnt[dst[i]], 1);
}

// dinv = rsqrt(cnt + 1)   (self loop adds 1)
__global__ void dinv_kernel(const int* __restrict__ cnt, float* __restrict__ dinv, int n) {
    int i = blockIdx.x * blockDim.x + threadIdx.x;
    if (i < n) dinv[i] = rsqrtf((float)(cnt[i] + 1));
}

// ---------------- 3-phase exclusive scan over cnt -> rowptr ----------------
__global__ __launch_bounds__(256) void scan1_kernel(const int* __restrict__ cnt,
                                                    int* __restrict__ rowptr,
                                                    int* __restrict__ bsums) {
    __shared__ int wsum[4];
    int tid = threadIdx.x;
    int lane = tid & 63;
    int wv = tid >> 6;
    int i0 = blockIdx.x * 1024 + tid * 4;
    int4 v = *(const int4*)&cnt[i0];
    int s = v.x + v.y + v.z + v.w;
    int inc = s;
#pragma unroll
    for (int off = 1; off < 64; off <<= 1) {
        int t = __shfl_up(inc, off, 64);
        if (lane >= off) inc += t;
    }
    if (lane == 63) wsum[wv] = inc;
    __syncthreads();
    int woff = 0;
#pragma unroll
    for (int w2 = 0; w2 < 4; ++w2)
        if (w2 < wv) woff += wsum[w2];
    int base = woff + inc - s;  // thread-exclusive
    int4 o;
    o.x = base;
    o.y = base + v.x;
    o.z = o.y + v.y;
    o.w = o.z + v.z;
    *(int4*)&rowptr[i0] = o;
    if (tid == 255) bsums[blockIdx.x] = woff + inc;
}

__global__ void scan2_kernel(int* __restrict__ bsums, int nb) {
    int lane = threadIdx.x;
    int v = (lane < nb) ? bsums[lane] : 0;
    int inc = v;
#pragma unroll
    for (int off = 1; off < 64; off <<= 1) {
        int t = __shfl_up(inc, off, 64);
        if (lane >= off) inc += t;
    }
    if (lane < nb) bsums[lane] = inc - v;
}

__global__ void scan3_kernel(int* __restrict__ rowptr, const int* __restrict__ bsums,
                             int* __restrict__ cursor, int n, int E) {
    int i = blockIdx.x * blockDim.x + threadIdx.x;
    if (i < n) {
        int val = rowptr[i] + bsums[i >> 10];
        rowptr[i] = val;
        cursor[i] = val;
    }
    if (i == 0) rowptr[n] = E;
}

// fill CSR: csr_src[pos] = src[e] bucketed by dst
__global__ void fill_kernel(const int* __restrict__ src, const int* __restrict__ dst,
                            int* __restrict__ cursor, int* __restrict__ csr_src, int E) {
    int i = blockIdx.x * blockDim.x + threadIdx.x;
    if (i < E) {
        int d = dst[i];
        int pos = atomicAdd(&cursor[d], 1);
        csr_src[pos] = src[i];
    }
}

// ---------------- GEMM: g = (x @ W) * dinv[row] ----------------
// 512 threads, 128 rows/block. W fully staged in LDS (64 KB).
// __launch_bounds__(512, 2): 2 blocks/CU -> VGPR cap 128 (matches the 64KB-LDS
// occupancy limit). (512,4) capped VGPR at 64 and spilled ~2GB/dispatch.
__global__ __launch_bounds__(512, 2) void gemm_kernel(
    const float* __restrict__ x, const float* __restrict__ W,
    const float* __restrict__ dinv, float* __restrict__ g, int n) {
    __shared__ float Wl[F * F];  // 64 KB
    int tid = threadIdx.x;
    {
        const float4* Wv = (const float4*)W;
        float4* Wlv = (float4*)Wl;
#pragma unroll
        for (int i = 0; i < 8; ++i) Wlv[tid + 512 * i] = Wv[tid + 512 * i];
    }
    __syncthreads();

    int c = (tid & 31) * 4;   // col base
    int rt = tid >> 5;        // 0..15
    int r0 = blockIdx.x * 128 + rt * 8;

    const float* xr[8];
#pragma unroll
    for (int i = 0; i < 8; ++i) xr[i] = x + (size_t)min(r0 + i, n - 1) * F;

    float4 acc[8] = {};

#pragma unroll
    for (int ch = 0; ch < 32; ++ch) {  // k chunks of 4
        int kc = ch * 4;
        float4 xv[8];
#pragma unroll
        for (int i = 0; i < 8; ++i) xv[i] = *(const float4*)(xr[i] + kc);
#pragma unroll
        for (int kk = 0; kk < 4; ++kk) {
            float4 w = *(const float4*)&Wl[(kc + kk) * F + c];
#pragma unroll
            for (int i = 0; i < 8; ++i) {
                float xs = ((const float*)&xv[i])[kk];
                acc[i].x += xs * w.x;
                acc[i].y += xs * w.y;
                acc[i].z += xs * w.z;
                acc[i].w += xs * w.w;
            }
        }
    }

#pragma unroll
    for (int i = 0; i < 8; ++i) {
        int rr = r0 + i;
        if (rr < n) {
            float di = dinv[rr];
            float4 o;
            o.x = acc[i].x * di;
            o.y = acc[i].y * di;
            o.z = acc[i].z * di;
            o.w = acc[i].w * di;
            *(float4*)&g[(size_t)rr * F + c] = o;
        }
    }
}

// ---------------- aggregate: out[d] = [relu](dinv[d]*(sum_{s in N(d)} g[s] + g[d]) + b) ----------------
template <bool RELU>
__global__ __launch_bounds__(256) void aggregate_kernel(
    const int* __restrict__ rowptr, const int* __restrict__ csr_src,
    const float* __restrict__ dinv, const float* __restrict__ g,
    const float* __restrict__ bias, float* __restrict__ out, int n) {
    int lane = threadIdx.x & 63;
    int d = (blockIdx.x * blockDim.x + threadIdx.x) >> 6;
    if (d >= n) return;
    int c = lane * 2;

    float2 acc = *(const float2*)&g[(size_t)d * F + c];  // self loop

    int e = rowptr[d];
    int end = rowptr[d + 1];
    for (; e + 4 <= end; e += 4) {
        int s0 = csr_src[e];
        int s1 = csr_src[e + 1];
        int s2 = csr_src[e + 2];
        int s3 = csr_src[e + 3];
        float2 v0 = *(const float2*)&g[(size_t)s0 * F + c];
        float2 v1 = *(const float2*)&g[(size_t)s1 * F + c];
        float2 v2 = *(const float2*)&g[(size_t)s2 * F + c];
        float2 v3 = *(const float2*)&g[(size_t)s3 * F + c];
        acc.x += v0.x + v1.x + v2.x + v3.x;
        acc.y += v0.y + v1.y + v2.y + v3.y;
    }
    for (; e < end; ++e) {
        int s = csr_src[e];
        float2 v = *(const float2*)&g[(size_t)s * F + c];
        acc.x += v.x;
        acc.y += v.y;
    }

    float di = dinv[d];
    float2 b = *(const float2*)&bias[c];
    float2 r;
    r.x = di * acc.x + b.x;
    r.y = di * acc.y + b.y;
    if (RELU) {
        r.x = fmaxf(r.x, 0.0f);
        r.y = fmaxf(r.y, 0.0f);
    }
    *(float2*)&out[(size_t)d * F + c] = r;
}

// ---------------- decode: out = sigmoid(dot(z[ls], z[ld])) ----------------
__global__ __launch_bounds__(256) void decode_kernel(
    const int* __restrict__ ls, const int* __restrict__ ld,
    const float* __restrict__ z, float* __restrict__ out, int EL) {
    int lane = threadIdx.x & 63;
    int w = (blockIdx.x * blockDim.x + threadIdx.x) >> 6;
    if (w >= EL) return;
    int a = ls[w];
    int b = ld[w];
    float2 va = *(const float2*)&z[(size_t)a * F + lane * 2];
    float2 vb = *(const float2*)&z[(size_t)b * F + lane * 2];
    float s = va.x * vb.x + va.y * vb.y;
#pragma unroll
    for (int off = 32; off; off >>= 1) s += __shfl_xor(s, off, 64);
    if (lane == 0) out[w] = 1.0f / (1.0f + expf(-s));
}

extern "C" void kernel_launch(void* const* d_in, const int* in_sizes, int n_in,
                              void* d_out, int out_size, void* d_ws, size_t ws_size,
                              hipStream_t stream) {
    const float* x = (const float*)d_in[0];
    const int* ei = (const int*)d_in[1];
    const int* eli = (const int*)d_in[2];
    const float* W1 = (const float*)d_in[3];
    const float* b1 = (const float*)d_in[4];
    const float* W2 = (const float*)d_in[5];
    const float* b2 = (const float*)d_in[6];
    float* out = (float*)d_out;

    int E = in_sizes[1] / 2;
    int EL = in_sizes[2] / 2;
    const int* src = ei;
    const int* dst = ei + E;
    const int* ls = eli;
    const int* ld = eli + EL;
    int n = in_sizes[0] / F;  // 50000

    int nb_scan = (n + 1023) / 1024;          // 49
    int npad = nb_scan * 1024;                // 50176

    char* ws = (char*)d_ws;
    float* dinv   = (float*)(ws);                        // [0,1MB)
    int*   rowptr = (int*)(ws + (1u << 20));             // [1MB,2MB): n+1 (padded writes ok)
    int*   cnt    = (int*)(ws + (2u << 20));             // 256KB
    int*   cursor = (int*)(ws + (2u << 20) + 262144u);   // 256KB
    int*   bsums  = (int*)(ws + (2u << 20) + 524288u);   // small
    int*   csr    = (int*)(ws + (3u << 20));             // [3MB,6.2MB): E ints
    float* bufA   = (float*)(ws + (8u << 20));           // g, 25.6MB
    float* bufB   = (float*)(ws + (8u << 20) + 26214400u);  // z1/z2, 25.6MB

    const int BS = 256;
    int nb_pad   = (npad + BS - 1) / BS;
    int nb_nodes = (n + BS - 1) / BS;
    int nb_edges = (E + BS - 1) / BS;
    int gemm_blocks = (n + 127) / 128;
    int agg_blocks = (n + 3) / 4;
    int dec_blocks = (EL + 3) / 4;

    // ---- CSR build ----
    zero_int_kernel<<<nb_pad, BS, 0, stream>>>(cnt, npad);
    deg_count_kernel<<<nb_edges, BS, 0, stream>>>(dst, cnt, E);
    dinv_kernel<<<nb_nodes, BS, 0, stream>>>(cnt, dinv, n);
    scan1_kernel<<<nb_scan, BS, 0, stream>>>(cnt, rowptr, bsums);
    scan2_kernel<<<1, 64, 0, stream>>>(bsums, nb_scan);
    scan3_kernel<<<nb_pad, BS, 0, stream>>>(rowptr, bsums, cursor, n, E);
    fill_kernel<<<nb_edges, BS, 0, stream>>>(src, dst, cursor, csr, E);

    // ---- layer 1 ----
    gemm_kernel<<<gemm_blocks, 512, 0, stream>>>(x, W1, dinv, bufA, n);
    aggregate_kernel<true><<<agg_blocks, BS, 0, stream>>>(rowptr, csr, dinv, bufA, b1, bufB, n);

    // ---- layer 2 ----
    gemm_kernel<<<gemm_blocks, 512, 0, stream>>>(bufB, W2, dinv, bufA, n);
    aggregate_kernel<false><<<agg_blocks, BS, 0, stream>>>(rowptr, csr, dinv, bufA, b2, bufB, n);

    // ---- decode ----
    decode_kernel<<<dec_blocks, BS, 0, stream>>>(ls, ld, bufB, out, EL);
}

// Round 5
// 337.451 us; speedup vs baseline: 7.8254x; 5.7526x over previous
//
#include <hip/hip_runtime.h>
#include <math.h>

#define NN 50000
#define F 128

// ---------------- small utility kernels ----------------
__global__ void zero_int_kernel(int* __restrict__ p, int n) {
    int i = blockIdx.x * blockDim.x + threadIdx.x;
    if (i < n) p[i] = 0;
}

// count in-degree (excl self loop) into cnt
__global__ void deg_count_kernel(const int* __restrict__ dst, int* __restrict__ cnt, int E) {
    int i = blockIdx.x * blockDim.x + threadIdx.x;
    if (i < E) atomicAdd(&cnt[dst[i]], 1);
}

// dinv = rsqrt(cnt + 1)   (self loop adds 1)
__global__ void dinv_kernel(const int* __restrict__ cnt, float* __restrict__ dinv, int n) {
    int i = blockIdx.x * blockDim.x + threadIdx.x;
    if (i < n) dinv[i] = rsqrtf((float)(cnt[i] + 1));
}

// ---------------- 3-phase exclusive scan over cnt -> rowptr ----------------
__global__ __launch_bounds__(256) void scan1_kernel(const int* __restrict__ cnt,
                                                    int* __restrict__ rowptr,
                                                    int* __restrict__ bsums) {
    __shared__ int wsum[4];
    int tid = threadIdx.x;
    int lane = tid & 63;
    int wv = tid >> 6;
    int i0 = blockIdx.x * 1024 + tid * 4;
    int4 v = *(const int4*)&cnt[i0];
    int s = v.x + v.y + v.z + v.w;
    int inc = s;
#pragma unroll
    for (int off = 1; off < 64; off <<= 1) {
        int t = __shfl_up(inc, off, 64);
        if (lane >= off) inc += t;
    }
    if (lane == 63) wsum[wv] = inc;
    __syncthreads();
    int woff = 0;
#pragma unroll
    for (int w2 = 0; w2 < 4; ++w2)
        if (w2 < wv) woff += wsum[w2];
    int base = woff + inc - s;  // thread-exclusive
    int4 o;
    o.x = base;
    o.y = base + v.x;
    o.z = o.y + v.y;
    o.w = o.z + v.z;
    *(int4*)&rowptr[i0] = o;
    if (tid == 255) bsums[blockIdx.x] = woff + inc;
}

__global__ void scan2_kernel(int* __restrict__ bsums, int nb) {
    int lane = threadIdx.x;
    int v = (lane < nb) ? bsums[lane] : 0;
    int inc = v;
#pragma unroll
    for (int off = 1; off < 64; off <<= 1) {
        int t = __shfl_up(inc, off, 64);
        if (lane >= off) inc += t;
    }
    if (lane < nb) bsums[lane] = inc - v;
}

__global__ void scan3_kernel(int* __restrict__ rowptr, const int* __restrict__ bsums,
                             int* __restrict__ cursor, int n, int E) {
    int i = blockIdx.x * blockDim.x + threadIdx.x;
    if (i < n) {
        int val = rowptr[i] + bsums[i >> 10];
        rowptr[i] = val;
        cursor[i] = val;
    }
    if (i == 0) rowptr[n] = E;
}

// fill CSR: csr_src[pos] = src[e] bucketed by dst
__global__ void fill_kernel(const int* __restrict__ src, const int* __restrict__ dst,
                            int* __restrict__ cursor, int* __restrict__ csr_src, int E) {
    int i = blockIdx.x * blockDim.x + threadIdx.x;
    if (i < E) {
        int d = dst[i];
        int pos = atomicAdd(&cursor[d], 1);
        csr_src[pos] = src[i];
    }
}

// ---------------- GEMM: g = (x @ W) * dinv[row] ----------------
// 512 threads, 64 rows/block, W fully staged in LDS (64 KB -> 2 blocks/CU).
// Thread = (colgrp tid&31)*(4 cols) x (rowthread tid>>5)*(4 rows) -> 16 accs.
// Hand-written 1-deep double buffer on x chunks; peeled last iteration.
// Deliberately small per-thread state (~70 VGPR) so no spills regardless of
// scheduler hoisting. (Full 32x unroll previously spilled ~2 GB/dispatch.)
__global__ __launch_bounds__(512, 2) void gemm_kernel(
    const float* __restrict__ x, const float* __restrict__ W,
    const float* __restrict__ dinv, float* __restrict__ g, int n) {
    __shared__ float Wl[F * F];  // 64 KB
    int tid = threadIdx.x;
    {
        const float4* Wv = (const float4*)W;
        float4* Wlv = (float4*)Wl;
#pragma unroll
        for (int i = 0; i < 8; ++i) Wlv[tid + 512 * i] = Wv[tid + 512 * i];
    }
    __syncthreads();

    int c = (tid & 31) * 4;   // col base
    int rt = tid >> 5;        // 0..15
    int r0 = blockIdx.x * 64 + rt * 4;

    const float* xr[4];
#pragma unroll
    for (int i = 0; i < 4; ++i) xr[i] = x + (size_t)min(r0 + i, n - 1) * F;

    float4 acc[4] = {};
    float4 xv[4];
#pragma unroll
    for (int i = 0; i < 4; ++i) xv[i] = *(const float4*)(xr[i]);

    for (int ch = 0; ch < 31; ++ch) {
        int kc = ch * 4;
        float4 xn[4];
#pragma unroll
        for (int i = 0; i < 4; ++i) xn[i] = *(const float4*)(xr[i] + kc + 4);
#pragma unroll
        for (int kk = 0; kk < 4; ++kk) {
            float4 w = *(const float4*)&Wl[(kc + kk) * F + c];
#pragma unroll
            for (int i = 0; i < 4; ++i) {
                float xs = ((const float*)&xv[i])[kk];
                acc[i].x += xs * w.x;
                acc[i].y += xs * w.y;
                acc[i].z += xs * w.z;
                acc[i].w += xs * w.w;
            }
        }
#pragma unroll
        for (int i = 0; i < 4; ++i) xv[i] = xn[i];
    }
    // peeled last chunk (kc = 124)
#pragma unroll
    for (int kk = 0; kk < 4; ++kk) {
        float4 w = *(const float4*)&Wl[(124 + kk) * F + c];
#pragma unroll
        for (int i = 0; i < 4; ++i) {
            float xs = ((const float*)&xv[i])[kk];
            acc[i].x += xs * w.x;
            acc[i].y += xs * w.y;
            acc[i].z += xs * w.z;
            acc[i].w += xs * w.w;
        }
    }

#pragma unroll
    for (int i = 0; i < 4; ++i) {
        int rr = r0 + i;
        if (rr < n) {
            float di = dinv[rr];
            float4 o;
            o.x = acc[i].x * di;
            o.y = acc[i].y * di;
            o.z = acc[i].z * di;
            o.w = acc[i].w * di;
            *(float4*)&g[(size_t)rr * F + c] = o;
        }
    }
}

// ---------------- aggregate: out[d] = [relu](dinv[d]*(sum_{s in N(d)} g[s] + g[d]) + b) ----------------
template <bool RELU>
__global__ __launch_bounds__(256) void aggregate_kernel(
    const int* __restrict__ rowptr, const int* __restrict__ csr_src,
    const float* __restrict__ dinv, const float* __restrict__ g,
    const float* __restrict__ bias, float* __restrict__ out, int n) {
    int lane = threadIdx.x & 63;
    int d = (blockIdx.x * blockDim.x + threadIdx.x) >> 6;
    if (d >= n) return;
    int c = lane * 2;

    float2 acc = *(const float2*)&g[(size_t)d * F + c];  // self loop

    int e = rowptr[d];
    int end = rowptr[d + 1];
    for (; e + 4 <= end; e += 4) {
        int s0 = csr_src[e];
        int s1 = csr_src[e + 1];
        int s2 = csr_src[e + 2];
        int s3 = csr_src[e + 3];
        float2 v0 = *(const float2*)&g[(size_t)s0 * F + c];
        float2 v1 = *(const float2*)&g[(size_t)s1 * F + c];
        float2 v2 = *(const float2*)&g[(size_t)s2 * F + c];
        float2 v3 = *(const float2*)&g[(size_t)s3 * F + c];
        acc.x += v0.x + v1.x + v2.x + v3.x;
        acc.y += v0.y + v1.y + v2.y + v3.y;
    }
    for (; e < end; ++e) {
        int s = csr_src[e];
        float2 v = *(const float2*)&g[(size_t)s * F + c];
        acc.x += v.x;
        acc.y += v.y;
    }

    float di = dinv[d];
    float2 b = *(const float2*)&bias[c];
    float2 r;
    r.x = di * acc.x + b.x;
    r.y = di * acc.y + b.y;
    if (RELU) {
        r.x = fmaxf(r.x, 0.0f);
        r.y = fmaxf(r.y, 0.0f);
    }
    *(float2*)&out[(size_t)d * F + c] = r;
}

// ---------------- decode: out = sigmoid(dot(z[ls], z[ld])) ----------------
__global__ __launch_bounds__(256) void decode_kernel(
    const int* __restrict__ ls, const int* __restrict__ ld,
    const float* __restrict__ z, float* __restrict__ out, int EL) {
    int lane = threadIdx.x & 63;
    int w = (blockIdx.x * blockDim.x + threadIdx.x) >> 6;
    if (w >= EL) return;
    int a = ls[w];
    int b = ld[w];
    float2 va = *(const float2*)&z[(size_t)a * F + lane * 2];
    float2 vb = *(const float2*)&z[(size_t)b * F + lane * 2];
    float s = va.x * vb.x + va.y * vb.y;
#pragma unroll
    for (int off = 32; off; off >>= 1) s += __shfl_xor(s, off, 64);
    if (lane == 0) out[w] = 1.0f / (1.0f + expf(-s));
}

extern "C" void kernel_launch(void* const* d_in, const int* in_sizes, int n_in,
                              void* d_out, int out_size, void* d_ws, size_t ws_size,
                              hipStream_t stream) {
    const float* x = (const float*)d_in[0];
    const int* ei = (const int*)d_in[1];
    const int* eli = (const int*)d_in[2];
    const float* W1 = (const float*)d_in[3];
    const float* b1 = (const float*)d_in[4];
    const float* W2 = (const float*)d_in[5];
    const float* b2 = (const float*)d_in[6];
    float* out = (float*)d_out;

    int E = in_sizes[1] / 2;
    int EL = in_sizes[2] / 2;
    const int* src = ei;
    const int* dst = ei + E;
    const int* ls = eli;
    const int* ld = eli + EL;
    int n = in_sizes[0] / F;  // 50000

    int nb_scan = (n + 1023) / 1024;          // 49
    int npad = nb_scan * 1024;                // 50176

    char* ws = (char*)d_ws;
    float* dinv   = (float*)(ws);                        // [0,1MB)
    int*   rowptr = (int*)(ws + (1u << 20));             // [1MB,2MB): n+1 (padded writes ok)
    int*   cnt    = (int*)(ws + (2u << 20));             // 256KB
    int*   cursor = (int*)(ws + (2u << 20) + 262144u);   // 256KB
    int*   bsums  = (int*)(ws + (2u << 20) + 524288u);   // small
    int*   csr    = (int*)(ws + (3u << 20));             // [3MB,6.2MB): E ints
    float* bufA   = (float*)(ws + (8u << 20));           // g, 25.6MB
    float* bufB   = (float*)(ws + (8u << 20) + 26214400u);  // z1/z2, 25.6MB

    const int BS = 256;
    int nb_pad   = (npad + BS - 1) / BS;
    int nb_nodes = (n + BS - 1) / BS;
    int nb_edges = (E + BS - 1) / BS;
    int gemm_blocks = (n + 63) / 64;
    int agg_blocks = (n + 3) / 4;
    int dec_blocks = (EL + 3) / 4;

    // ---- CSR build ----
    zero_int_kernel<<<nb_pad, BS, 0, stream>>>(cnt, npad);
    deg_count_kernel<<<nb_edges, BS, 0, stream>>>(dst, cnt, E);
    dinv_kernel<<<nb_nodes, BS, 0, stream>>>(cnt, dinv, n);
    scan1_kernel<<<nb_scan, BS, 0, stream>>>(cnt, rowptr, bsums);
    scan2_kernel<<<1, 64, 0, stream>>>(bsums, nb_scan);
    scan3_kernel<<<nb_pad, BS, 0, stream>>>(rowptr, bsums, cursor, n, E);
    fill_kernel<<<nb_edges, BS, 0, stream>>>(src, dst, cursor, csr, E);

    // ---- layer 1 ----
    gemm_kernel<<<gemm_blocks, 512, 0, stream>>>(x, W1, dinv, bufA, n);
    aggregate_kernel<true><<<agg_blocks, BS, 0, stream>>>(rowptr, csr, dinv, bufA, b1, bufB, n);

    // ---- layer 2 ----
    gemm_kernel<<<gemm_blocks, 512, 0, stream>>>(bufB, W2, dinv, bufA, n);
    aggregate_kernel<false><<<agg_blocks, BS, 0, stream>>>(rowptr, csr, dinv, bufA, b2, bufB, n);

    // ---- decode ----
    decode_kernel<<<dec_blocks, BS, 0, stream>>>(ls, ld, bufB, out, EL);
}

// Round 6
// 287.801 us; speedup vs baseline: 9.1754x; 1.1725x over previous
//
#include <hip/hip_runtime.h>
#include <hip/hip_fp16.h>
#include <math.h>

#define NN 50000
#define F 128

// ---------------- small utility kernels ----------------
__global__ void zero_int_kernel(int* __restrict__ p, int n) {
    int i = blockIdx.x * blockDim.x + threadIdx.x;
    if (i < n) p[i] = 0;
}

// count in-degree (excl self loop) into cnt
__global__ void deg_count_kernel(const int* __restrict__ dst, int* __restrict__ cnt, int E) {
    int i = blockIdx.x * blockDim.x + threadIdx.x;
    if (i < E) atomicAdd(&cnt[dst[i]], 1);
}

// dinv = rsqrt(cnt + 1)   (self loop adds 1)
__global__ void dinv_kernel(const int* __restrict__ cnt, float* __restrict__ dinv, int n) {
    int i = blockIdx.x * blockDim.x + threadIdx.x;
    if (i < n) dinv[i] = rsqrtf((float)(cnt[i] + 1));
}

// ---------------- 3-phase exclusive scan over cnt -> rowptr ----------------
__global__ __launch_bounds__(256) void scan1_kernel(const int* __restrict__ cnt,
                                                    int* __restrict__ rowptr,
                                                    int* __restrict__ bsums) {
    __shared__ int wsum[4];
    int tid = threadIdx.x;
    int lane = tid & 63;
    int wv = tid >> 6;
    int i0 = blockIdx.x * 1024 + tid * 4;
    int4 v = *(const int4*)&cnt[i0];
    int s = v.x + v.y + v.z + v.w;
    int inc = s;
#pragma unroll
    for (int off = 1; off < 64; off <<= 1) {
        int t = __shfl_up(inc, off, 64);
        if (lane >= off) inc += t;
    }
    if (lane == 63) wsum[wv] = inc;
    __syncthreads();
    int woff = 0;
#pragma unroll
    for (int w2 = 0; w2 < 4; ++w2)
        if (w2 < wv) woff += wsum[w2];
    int base = woff + inc - s;  // thread-exclusive
    int4 o;
    o.x = base;
    o.y = base + v.x;
    o.z = o.y + v.y;
    o.w = o.z + v.z;
    *(int4*)&rowptr[i0] = o;
    if (tid == 255) bsums[blockIdx.x] = woff + inc;
}

__global__ void scan2_kernel(int* __restrict__ bsums, int nb) {
    int lane = threadIdx.x;
    int v = (lane < nb) ? bsums[lane] : 0;
    int inc = v;
#pragma unroll
    for (int off = 1; off < 64; off <<= 1) {
        int t = __shfl_up(inc, off, 64);
        if (lane >= off) inc += t;
    }
    if (lane < nb) bsums[lane] = inc - v;
}

__global__ void scan3_kernel(int* __restrict__ rowptr, const int* __restrict__ bsums,
                             int* __restrict__ cursor, int n, int E) {
    int i = blockIdx.x * blockDim.x + threadIdx.x;
    if (i < n) {
        int val = rowptr[i] + bsums[i >> 10];
        rowptr[i] = val;
        cursor[i] = val;
    }
    if (i == 0) rowptr[n] = E;
}

// fill CSR: csr_src[pos] = src[e] bucketed by dst
__global__ void fill_kernel(const int* __restrict__ src, const int* __restrict__ dst,
                            int* __restrict__ cursor, int* __restrict__ csr_src, int E) {
    int i = blockIdx.x * blockDim.x + threadIdx.x;
    if (i < E) {
        int d = dst[i];
        int pos = atomicAdd(&cursor[d], 1);
        csr_src[pos] = src[i];
    }
}

// ---------------- GEMM: g = (x @ W) * dinv[row], fp16 output ----------------
// 512 threads, 64 rows/block, W fully staged in LDS (64 KB -> 2 blocks/CU).
// Thread = (colgrp tid&31)*(4 cols) x (rowthread tid>>5)*(4 rows) -> 16 accs.
// Hand-written 1-deep double buffer on x chunks; peeled last iteration.
// (Full 32x unroll spilled ~2 GB/dispatch; launch_bounds 2nd arg = blocks/CU.)
__global__ __launch_bounds__(512, 2) void gemm_kernel(
    const float* __restrict__ x, const float* __restrict__ W,
    const float* __restrict__ dinv, __half* __restrict__ g, int n) {
    __shared__ float Wl[F * F];  // 64 KB
    int tid = threadIdx.x;
    {
        const float4* Wv = (const float4*)W;
        float4* Wlv = (float4*)Wl;
#pragma unroll
        for (int i = 0; i < 8; ++i) Wlv[tid + 512 * i] = Wv[tid + 512 * i];
    }
    __syncthreads();

    int c = (tid & 31) * 4;   // col base
    int rt = tid >> 5;        // 0..15
    int r0 = blockIdx.x * 64 + rt * 4;

    const float* xr[4];
#pragma unroll
    for (int i = 0; i < 4; ++i) xr[i] = x + (size_t)min(r0 + i, n - 1) * F;

    float4 acc[4] = {};
    float4 xv[4];
#pragma unroll
    for (int i = 0; i < 4; ++i) xv[i] = *(const float4*)(xr[i]);

    for (int ch = 0; ch < 31; ++ch) {
        int kc = ch * 4;
        float4 xn[4];
#pragma unroll
        for (int i = 0; i < 4; ++i) xn[i] = *(const float4*)(xr[i] + kc + 4);
#pragma unroll
        for (int kk = 0; kk < 4; ++kk) {
            float4 w = *(const float4*)&Wl[(kc + kk) * F + c];
#pragma unroll
            for (int i = 0; i < 4; ++i) {
                float xs = ((const float*)&xv[i])[kk];
                acc[i].x += xs * w.x;
                acc[i].y += xs * w.y;
                acc[i].z += xs * w.z;
                acc[i].w += xs * w.w;
            }
        }
#pragma unroll
        for (int i = 0; i < 4; ++i) xv[i] = xn[i];
    }
    // peeled last chunk (kc = 124)
#pragma unroll
    for (int kk = 0; kk < 4; ++kk) {
        float4 w = *(const float4*)&Wl[(124 + kk) * F + c];
#pragma unroll
        for (int i = 0; i < 4; ++i) {
            float xs = ((const float*)&xv[i])[kk];
            acc[i].x += xs * w.x;
            acc[i].y += xs * w.y;
            acc[i].z += xs * w.z;
            acc[i].w += xs * w.w;
        }
    }

#pragma unroll
    for (int i = 0; i < 4; ++i) {
        int rr = r0 + i;
        if (rr < n) {
            float di = dinv[rr];
            union { __half2 h[2]; uint2 u; } pk;
            pk.h[0] = __floats2half2_rn(acc[i].x * di, acc[i].y * di);
            pk.h[1] = __floats2half2_rn(acc[i].z * di, acc[i].w * di);
            *(uint2*)&g[(size_t)rr * F + c] = pk.u;
        }
    }
}

// ---------------- aggregate ----------------
// out[d] = [relu](dinv[d]*(sum_{s in N(d)} g[s] + g[d]) + b)
// g is fp16 [n][128]; one wave per dst node, __half2 (2 cols, 4B) per lane.
// OUT_HALF: write fp16 (for the decode-gathered z2), else f32.
template <bool RELU, bool OUT_HALF>
__global__ __launch_bounds__(256) void aggregate_kernel(
    const int* __restrict__ rowptr, const int* __restrict__ csr_src,
    const float* __restrict__ dinv, const __half* __restrict__ g,
    const float* __restrict__ bias, void* __restrict__ out, int n) {
    int lane = threadIdx.x & 63;
    int d = (blockIdx.x * blockDim.x + threadIdx.x) >> 6;
    if (d >= n) return;

    const __half2* gp = (const __half2*)g;  // [n][64]

    float2 f = __half22float2(gp[(size_t)d * 64 + lane]);  // self loop
    float accx = f.x, accy = f.y;

    int e = rowptr[d];
    int end = rowptr[d + 1];
    for (; e + 8 <= end; e += 8) {
        __half2 v[8];
#pragma unroll
        for (int j = 0; j < 8; ++j) {
            int s = csr_src[e + j];
            v[j] = gp[(size_t)s * 64 + lane];
        }
#pragma unroll
        for (int j = 0; j < 8; ++j) {
            float2 fv = __half22float2(v[j]);
            accx += fv.x;
            accy += fv.y;
        }
    }
    for (; e < end; ++e) {
        int s = csr_src[e];
        float2 fv = __half22float2(gp[(size_t)s * 64 + lane]);
        accx += fv.x;
        accy += fv.y;
    }

    float di = dinv[d];
    int c = lane * 2;
    float2 b = *(const float2*)&bias[c];
    float rx = di * accx + b.x;
    float ry = di * accy + b.y;
    if (RELU) {
        rx = fmaxf(rx, 0.0f);
        ry = fmaxf(ry, 0.0f);
    }
    if (OUT_HALF) {
        ((__half2*)out)[(size_t)d * 64 + lane] = __floats2half2_rn(rx, ry);
    } else {
        float2 r = {rx, ry};
        *(float2*)&((float*)out)[(size_t)d * F + c] = r;
    }
}

// ---------------- decode: out = sigmoid(dot(z[ls], z[ld])), z fp16 ----------------
__global__ __launch_bounds__(256) void decode_kernel(
    const int* __restrict__ ls, const int* __restrict__ ld,
    const __half* __restrict__ z, float* __restrict__ out, int EL) {
    int lane = threadIdx.x & 63;
    int w = (blockIdx.x * blockDim.x + threadIdx.x) >> 6;
    if (w >= EL) return;
    int a = ls[w];
    int b = ld[w];
    const __half2* zp = (const __half2*)z;
    float2 va = __half22float2(zp[(size_t)a * 64 + lane]);
    float2 vb = __half22float2(zp[(size_t)b * 64 + lane]);
    float s = va.x * vb.x + va.y * vb.y;
#pragma unroll
    for (int off = 32; off; off >>= 1) s += __shfl_xor(s, off, 64);
    if (lane == 0) out[w] = 1.0f / (1.0f + expf(-s));
}

extern "C" void kernel_launch(void* const* d_in, const int* in_sizes, int n_in,
                              void* d_out, int out_size, void* d_ws, size_t ws_size,
                              hipStream_t stream) {
    const float* x = (const float*)d_in[0];
    const int* ei = (const int*)d_in[1];
    const int* eli = (const int*)d_in[2];
    const float* W1 = (const float*)d_in[3];
    const float* b1 = (const float*)d_in[4];
    const float* W2 = (const float*)d_in[5];
    const float* b2 = (const float*)d_in[6];
    float* out = (float*)d_out;

    int E = in_sizes[1] / 2;
    int EL = in_sizes[2] / 2;
    const int* src = ei;
    const int* dst = ei + E;
    const int* ls = eli;
    const int* ld = eli + EL;
    int n = in_sizes[0] / F;  // 50000

    int nb_scan = (n + 1023) / 1024;          // 49
    int npad = nb_scan * 1024;                // 50176

    char* ws = (char*)d_ws;
    float*  dinv   = (float*)(ws);                        // [0,1MB)
    int*    rowptr = (int*)(ws + (1u << 20));             // [1MB,2MB)
    int*    cnt    = (int*)(ws + (2u << 20));             // 256KB
    int*    cursor = (int*)(ws + (2u << 20) + 262144u);   // 256KB
    int*    bsums  = (int*)(ws + (2u << 20) + 524288u);   // small
    int*    csr    = (int*)(ws + (3u << 20));             // [3MB,6.2MB)
    __half* gh     = (__half*)(ws + (8u << 20));          // fp16 g, 12.8MB [8,21MB)
    float*  z1     = (float*)(ws + (21u << 20));          // f32 z1, 25.6MB [21,47MB)
    __half* z2     = (__half*)(ws + (47u << 20));         // fp16 z2, 12.8MB [47,60MB)

    const int BS = 256;
    int nb_pad   = (npad + BS - 1) / BS;
    int nb_nodes = (n + BS - 1) / BS;
    int nb_edges = (E + BS - 1) / BS;
    int gemm_blocks = (n + 63) / 64;
    int agg_blocks = (n + 3) / 4;
    int dec_blocks = (EL + 3) / 4;

    // ---- CSR build ----
    zero_int_kernel<<<nb_pad, BS, 0, stream>>>(cnt, npad);
    deg_count_kernel<<<nb_edges, BS, 0, stream>>>(dst, cnt, E);
    dinv_kernel<<<nb_nodes, BS, 0, stream>>>(cnt, dinv, n);
    scan1_kernel<<<nb_scan, BS, 0, stream>>>(cnt, rowptr, bsums);
    scan2_kernel<<<1, 64, 0, stream>>>(bsums, nb_scan);
    scan3_kernel<<<nb_pad, BS, 0, stream>>>(rowptr, bsums, cursor, n, E);
    fill_kernel<<<nb_edges, BS, 0, stream>>>(src, dst, cursor, csr, E);

    // ---- layer 1: gh = fp16((x@W1)*dinv) ; z1 = relu(dinv*(sum gh + gh) + b1) ----
    gemm_kernel<<<gemm_blocks, 512, 0, stream>>>(x, W1, dinv, gh, n);
    aggregate_kernel<true, false><<<agg_blocks, BS, 0, stream>>>(rowptr, csr, dinv, gh, b1, z1, n);

    // ---- layer 2: gh = fp16((z1@W2)*dinv) ; z2 = fp16(dinv*(sum gh + gh) + b2) ----
    gemm_kernel<<<gemm_blocks, 512, 0, stream>>>(z1, W2, dinv, gh, n);
    aggregate_kernel<false, true><<<agg_blocks, BS, 0, stream>>>(rowptr, csr, dinv, gh, b2, z2, n);

    // ---- decode ----
    decode_kernel<<<dec_blocks, BS, 0, stream>>>(ls, ld, z2, out, EL);
}

// Round 7
// 249.817 us; speedup vs baseline: 10.5705x; 1.1520x over previous
//
#include <hip/hip_runtime.h>
#include <hip/hip_fp16.h>
#include <math.h>

#define NN 50000
#define F 128
#define NB 64  // partition blocks

// ---------------- CSR build via 2-level radix partition by dst ----------------
// Pass 1: per-block LDS histogram of coarse bucket (dst>>8)
__global__ __launch_bounds__(256) void hist_kernel(const int* __restrict__ dst,
                                                   int* __restrict__ blockhist, int E) {
    __shared__ int h[256];
    int t = threadIdx.x;
    h[t] = 0;
    __syncthreads();
    int chunk = (E + NB - 1) / NB;
    int s = blockIdx.x * chunk;
    int e = min(E, s + chunk);
    for (int i = s + t; i < e; i += 256) atomicAdd(&h[dst[i] >> 8], 1);
    __syncthreads();
    blockhist[t * NB + blockIdx.x] = h[t];  // [bucket][block]
}

// Pass 2 (1 block): bucket totals -> bucket_start; rewrite blockhist to offsets
__global__ __launch_bounds__(256) void scanbuckets_kernel(int* __restrict__ blockhist,
                                                          int* __restrict__ bstart, int E) {
    __shared__ int wtot[4];
    int t = threadIdx.x;
    int base = t * NB;
    int sum = 0;
#pragma unroll 8
    for (int j = 0; j < NB; ++j) sum += blockhist[base + j];
    int lane = t & 63, wv = t >> 6;
    int inc = sum;
#pragma unroll
    for (int o = 1; o < 64; o <<= 1) {
        int u = __shfl_up(inc, o, 64);
        if (lane >= o) inc += u;
    }
    if (lane == 63) wtot[wv] = inc;
    __syncthreads();
    int wo = 0;
#pragma unroll
    for (int w2 = 0; w2 < 4; ++w2)
        if (w2 < wv) wo += wtot[w2];
    int excl = wo + inc - sum;
    bstart[t] = excl;
    if (t == 255) bstart[256] = excl + sum;  // == E
    int run = excl;
    for (int j = 0; j < NB; ++j) {
        int v = blockhist[base + j];
        blockhist[base + j] = run;
        run += v;
    }
}

// Pass 3: scatter packed (dst&255)<<16 | src into bucket-contiguous ranges
__global__ __launch_bounds__(256) void part_kernel(const int* __restrict__ src,
                                                   const int* __restrict__ dst,
                                                   const int* __restrict__ blockhist,
                                                   unsigned int* __restrict__ part, int E) {
    __shared__ int cur[256];
    int t = threadIdx.x;
    cur[t] = blockhist[t * NB + blockIdx.x];
    __syncthreads();
    int chunk = (E + NB - 1) / NB;
    int s = blockIdx.x * chunk;
    int e = min(E, s + chunk);
    for (int i = s + t; i < e; i += 256) {
        int dd = dst[i];
        int p = atomicAdd(&cur[dd >> 8], 1);
        part[p] = ((unsigned int)(dd & 255) << 16) | (unsigned int)src[i];
    }
}

// Pass 4: one block per coarse bucket: LDS counting sort by dst&255;
// emits csr (u16 src), rowptr and dinv for the bucket's 256 nodes.
__global__ __launch_bounds__(256) void bucket_kernel(
    const unsigned int* __restrict__ part, const int* __restrict__ bstart,
    int* __restrict__ rowptr, float* __restrict__ dinv,
    unsigned short* __restrict__ csr, int n, int E, int nbuck) {
    __shared__ int cnt[256];
    __shared__ int wtot[4];
    __shared__ unsigned int stage[8192];
    int b = blockIdx.x;
    int t = threadIdx.x;
    int s = bstart[b];
    int e = bstart[b + 1];
    int m = e - s;
    cnt[t] = 0;
    __syncthreads();
    bool fits = (m <= 8192);
    for (int i = t; i < m; i += 256) {
        unsigned int v = part[s + i];
        if (fits) stage[i] = v;
        atomicAdd(&cnt[(v >> 16) & 255], 1);
    }
    __syncthreads();
    int c = cnt[t];
    int lane = t & 63, wv = t >> 6;
    int inc = c;
#pragma unroll
    for (int o = 1; o < 64; o <<= 1) {
        int u = __shfl_up(inc, o, 64);
        if (lane >= o) inc += u;
    }
    if (lane == 63) wtot[wv] = inc;
    __syncthreads();
    int wo = 0;
#pragma unroll
    for (int w2 = 0; w2 < 4; ++w2)
        if (w2 < wv) wo += wtot[w2];
    int excl = wo + inc - c;  // exclusive scan of cnt within bucket
    int d = (b << 8) + t;
    if (d < n) {
        rowptr[d] = s + excl;
        dinv[d] = rsqrtf((float)(c + 1));
    }
    if (b == nbuck - 1 && t == 255) rowptr[n] = E;
    __syncthreads();
    cnt[t] = excl;  // reuse as cursor
    __syncthreads();
    if (fits) {
        for (int i = t; i < m; i += 256) {
            unsigned int v = stage[i];
            int p = atomicAdd(&cnt[(v >> 16) & 255], 1);
            csr[s + p] = (unsigned short)(v & 0xFFFFu);
        }
    } else {
        for (int i = t; i < m; i += 256) {
            unsigned int v = part[s + i];
            int p = atomicAdd(&cnt[(v >> 16) & 255], 1);
            csr[s + p] = (unsigned short)(v & 0xFFFFu);
        }
    }
}

// ---------------- GEMM: g = (x @ W) * dinv[row], fp16 output ----------------
// 512 threads, 64 rows/block, W fully staged in LDS (64 KB -> 2 blocks/CU).
// Hand-written 1-deep double buffer on x chunks; peeled last iteration.
// (Full 32x unroll spilled ~2 GB/dispatch; launch_bounds 2nd arg = blocks/CU.)
__global__ __launch_bounds__(512, 2) void gemm_kernel(
    const float* __restrict__ x, const float* __restrict__ W,
    const float* __restrict__ dinv, __half* __restrict__ g, int n) {
    __shared__ float Wl[F * F];  // 64 KB
    int tid = threadIdx.x;
    {
        const float4* Wv = (const float4*)W;
        float4* Wlv = (float4*)Wl;
#pragma unroll
        for (int i = 0; i < 8; ++i) Wlv[tid + 512 * i] = Wv[tid + 512 * i];
    }
    __syncthreads();

    int c = (tid & 31) * 4;   // col base
    int rt = tid >> 5;        // 0..15
    int r0 = blockIdx.x * 64 + rt * 4;

    const float* xr[4];
#pragma unroll
    for (int i = 0; i < 4; ++i) xr[i] = x + (size_t)min(r0 + i, n - 1) * F;

    float4 acc[4] = {};
    float4 xv[4];
#pragma unroll
    for (int i = 0; i < 4; ++i) xv[i] = *(const float4*)(xr[i]);

    for (int ch = 0; ch < 31; ++ch) {
        int kc = ch * 4;
        float4 xn[4];
#pragma unroll
        for (int i = 0; i < 4; ++i) xn[i] = *(const float4*)(xr[i] + kc + 4);
#pragma unroll
        for (int kk = 0; kk < 4; ++kk) {
            float4 w = *(const float4*)&Wl[(kc + kk) * F + c];
#pragma unroll
            for (int i = 0; i < 4; ++i) {
                float xs = ((const float*)&xv[i])[kk];
                acc[i].x += xs * w.x;
                acc[i].y += xs * w.y;
                acc[i].z += xs * w.z;
                acc[i].w += xs * w.w;
            }
        }
#pragma unroll
        for (int i = 0; i < 4; ++i) xv[i] = xn[i];
    }
    // peeled last chunk (kc = 124)
#pragma unroll
    for (int kk = 0; kk < 4; ++kk) {
        float4 w = *(const float4*)&Wl[(124 + kk) * F + c];
#pragma unroll
        for (int i = 0; i < 4; ++i) {
            float xs = ((const float*)&xv[i])[kk];
            acc[i].x += xs * w.x;
            acc[i].y += xs * w.y;
            acc[i].z += xs * w.z;
            acc[i].w += xs * w.w;
        }
    }

#pragma unroll
    for (int i = 0; i < 4; ++i) {
        int rr = r0 + i;
        if (rr < n) {
            float di = dinv[rr];
            union { __half2 h[2]; uint2 u; } pk;
            pk.h[0] = __floats2half2_rn(acc[i].x * di, acc[i].y * di);
            pk.h[1] = __floats2half2_rn(acc[i].z * di, acc[i].w * di);
            *(uint2*)&g[(size_t)rr * F + c] = pk.u;
        }
    }
}

// ---------------- aggregate ----------------
// out[d] = [relu](dinv[d]*(sum_{s in N(d)} g[s] + g[d]) + b)
// g fp16 [n][128]; one wave per dst node, __half2 per lane. csr is u16.
template <bool RELU, bool OUT_HALF>
__global__ __launch_bounds__(256) void aggregate_kernel(
    const int* __restrict__ rowptr, const unsigned short* __restrict__ csr_src,
    const float* __restrict__ dinv, const __half* __restrict__ g,
    const float* __restrict__ bias, void* __restrict__ out, int n) {
    int lane = threadIdx.x & 63;
    int d = (blockIdx.x * blockDim.x + threadIdx.x) >> 6;
    if (d >= n) return;

    const __half2* gp = (const __half2*)g;  // [n][64]

    float2 f = __half22float2(gp[(size_t)d * 64 + lane]);  // self loop
    float accx = f.x, accy = f.y;

    int e = rowptr[d];
    int end = rowptr[d + 1];
    for (; e + 8 <= end; e += 8) {
        __half2 v[8];
#pragma unroll
        for (int j = 0; j < 8; ++j) {
            int s = csr_src[e + j];
            v[j] = gp[(size_t)s * 64 + lane];
        }
#pragma unroll
        for (int j = 0; j < 8; ++j) {
            float2 fv = __half22float2(v[j]);
            accx += fv.x;
            accy += fv.y;
        }
    }
    for (; e < end; ++e) {
        int s = csr_src[e];
        float2 fv = __half22float2(gp[(size_t)s * 64 + lane]);
        accx += fv.x;
        accy += fv.y;
    }

    float di = dinv[d];
    int c = lane * 2;
    float2 b = *(const float2*)&bias[c];
    float rx = di * accx + b.x;
    float ry = di * accy + b.y;
    if (RELU) {
        rx = fmaxf(rx, 0.0f);
        ry = fmaxf(ry, 0.0f);
    }
    if (OUT_HALF) {
        ((__half2*)out)[(size_t)d * 64 + lane] = __floats2half2_rn(rx, ry);
    } else {
        float2 r = {rx, ry};
        *(float2*)&((float*)out)[(size_t)d * F + c] = r;
    }
}

// ---------------- decode: out = sigmoid(dot(z[ls], z[ld])), z fp16 ----------------
__global__ __launch_bounds__(256) void decode_kernel(
    const int* __restrict__ ls, const int* __restrict__ ld,
    const __half* __restrict__ z, float* __restrict__ out, int EL) {
    int lane = threadIdx.x & 63;
    int w = (blockIdx.x * blockDim.x + threadIdx.x) >> 6;
    if (w >= EL) return;
    int a = ls[w];
    int b = ld[w];
    const __half2* zp = (const __half2*)z;
    float2 va = __half22float2(zp[(size_t)a * 64 + lane]);
    float2 vb = __half22float2(zp[(size_t)b * 64 + lane]);
    float s = va.x * vb.x + va.y * vb.y;
#pragma unroll
    for (int off = 32; off; off >>= 1) s += __shfl_xor(s, off, 64);
    if (lane == 0) out[w] = 1.0f / (1.0f + expf(-s));
}

extern "C" void kernel_launch(void* const* d_in, const int* in_sizes, int n_in,
                              void* d_out, int out_size, void* d_ws, size_t ws_size,
                              hipStream_t stream) {
    const float* x = (const float*)d_in[0];
    const int* ei = (const int*)d_in[1];
    const int* eli = (const int*)d_in[2];
    const float* W1 = (const float*)d_in[3];
    const float* b1 = (const float*)d_in[4];
    const float* W2 = (const float*)d_in[5];
    const float* b2 = (const float*)d_in[6];
    float* out = (float*)d_out;

    int E = in_sizes[1] / 2;
    int EL = in_sizes[2] / 2;
    const int* src = ei;
    const int* dst = ei + E;
    const int* ls = eli;
    const int* ld = eli + EL;
    int n = in_sizes[0] / F;  // 50000
    int nbuck = (n + 255) >> 8;  // 196

    char* ws = (char*)d_ws;
    float*          dinv      = (float*)(ws);                       // [0, 1MB)
    int*            rowptr    = (int*)(ws + (1u << 20));            // [1MB, 2MB): n+1
    int*            blockhist = (int*)(ws + 1572864u);              // [1.5MB): 256*NB ints
    int*            bstart    = (int*)(ws + 1900544u);              // [~1.81MB): 257 ints
    unsigned int*   part      = (unsigned int*)(ws + (3u << 20));   // [3MB, 6.2MB)
    unsigned short* csr       = (unsigned short*)(ws + 6815744u);   // [6.5MB, 8.1MB)
    __half*         gh        = (__half*)(ws + (9u << 20));         // [9MB, 21.8MB)
    float*          z1        = (float*)(ws + (22u << 20));         // [22MB, 47.6MB)
    __half*         z2        = (__half*)(ws + (48u << 20));        // [48MB, 60.8MB)

    const int BS = 256;
    int gemm_blocks = (n + 63) / 64;
    int agg_blocks = (n + 3) / 4;
    int dec_blocks = (EL + 3) / 4;

    // ---- CSR build (radix partition by dst; also emits rowptr + dinv) ----
    hist_kernel<<<NB, BS, 0, stream>>>(dst, blockhist, E);
    scanbuckets_kernel<<<1, BS, 0, stream>>>(blockhist, bstart, E);
    part_kernel<<<NB, BS, 0, stream>>>(src, dst, blockhist, part, E);
    bucket_kernel<<<nbuck, BS, 0, stream>>>(part, bstart, rowptr, dinv, csr, n, E, nbuck);

    // ---- layer 1: gh = fp16((x@W1)*dinv) ; z1 = relu(dinv*(sum gh + gh) + b1) ----
    gemm_kernel<<<gemm_blocks, 512, 0, stream>>>(x, W1, dinv, gh, n);
    aggregate_kernel<true, false><<<agg_blocks, BS, 0, stream>>>(rowptr, csr, dinv, gh, b1, z1, n);

    // ---- layer 2: gh = fp16((z1@W2)*dinv) ; z2 = fp16(dinv*(sum gh + gh) + b2) ----
    gemm_kernel<<<gemm_blocks, 512, 0, stream>>>(z1, W2, dinv, gh, n);
    aggregate_kernel<false, true><<<agg_blocks, BS, 0, stream>>>(rowptr, csr, dinv, gh, b2, z2, n);

    // ---- decode ----
    decode_kernel<<<dec_blocks, BS, 0, stream>>>(ls, ld, z2, out, EL);
}

// Round 8
// 238.561 us; speedup vs baseline: 11.0692x; 1.0472x over previous
//
#include <hip/hip_runtime.h>
#include <hip/hip_fp16.h>
#include <math.h>

#define NN 50000
#define F 128
#define NB 512  // partition blocks

typedef _Float16 half8 __attribute__((ext_vector_type(8)));
typedef float floatx4 __attribute__((ext_vector_type(4)));
typedef unsigned int uintx4 __attribute__((ext_vector_type(4)));

// ---------------- CSR build via 2-level radix partition by dst ----------------
// Pass 1: per-block LDS histogram of coarse bucket (dst>>8). blockhist[block][bucket].
__global__ __launch_bounds__(256) void hist_kernel(const int* __restrict__ dst,
                                                   int* __restrict__ blockhist, int E) {
    __shared__ int h[256];
    int t = threadIdx.x;
    h[t] = 0;
    __syncthreads();
    int chunk = (E + NB - 1) / NB;
    int s = blockIdx.x * chunk;
    int e = min(E, s + chunk);
    for (int i = s + t; i < e; i += 256) atomicAdd(&h[dst[i] >> 8], 1);
    __syncthreads();
    blockhist[blockIdx.x * 256 + t] = h[t];
}

// Pass 2 (1 block): bucket totals -> bucket_start; rewrite blockhist to offsets
__global__ __launch_bounds__(256) void scanbuckets_kernel(int* __restrict__ blockhist,
                                                          int* __restrict__ bstart, int E) {
    __shared__ int wtot[4];
    int t = threadIdx.x;
    int sum = 0;
#pragma unroll 8
    for (int j = 0; j < NB; ++j) sum += blockhist[j * 256 + t];
    int lane = t & 63, wv = t >> 6;
    int inc = sum;
#pragma unroll
    for (int o = 1; o < 64; o <<= 1) {
        int u = __shfl_up(inc, o, 64);
        if (lane >= o) inc += u;
    }
    if (lane == 63) wtot[wv] = inc;
    __syncthreads();
    int wo = 0;
#pragma unroll
    for (int w2 = 0; w2 < 4; ++w2)
        if (w2 < wv) wo += wtot[w2];
    int excl = wo + inc - sum;
    bstart[t] = excl;
    if (t == 255) bstart[256] = excl + sum;  // == E
    int run = excl;
#pragma unroll 4
    for (int j = 0; j < NB; ++j) {
        int v = blockhist[j * 256 + t];
        blockhist[j * 256 + t] = run;
        run += v;
    }
}

// Pass 3: scatter packed (dst&255)<<16 | src into bucket-contiguous ranges
__global__ __launch_bounds__(256) void part_kernel(const int* __restrict__ src,
                                                   const int* __restrict__ dst,
                                                   const int* __restrict__ blockhist,
                                                   unsigned int* __restrict__ part, int E) {
    __shared__ int cur[256];
    int t = threadIdx.x;
    cur[t] = blockhist[blockIdx.x * 256 + t];
    __syncthreads();
    int chunk = (E + NB - 1) / NB;
    int s = blockIdx.x * chunk;
    int e = min(E, s + chunk);
    for (int i = s + t; i < e; i += 256) {
        int dd = dst[i];
        int p = atomicAdd(&cur[dd >> 8], 1);
        part[p] = ((unsigned int)(dd & 255) << 16) | (unsigned int)src[i];
    }
}

// Pass 4: one block per coarse bucket: LDS counting sort by dst&255;
// emits csr (u16 src), rowptr and dinv for the bucket's 256 nodes.
__global__ __launch_bounds__(256) void bucket_kernel(
    const unsigned int* __restrict__ part, const int* __restrict__ bstart,
    int* __restrict__ rowptr, float* __restrict__ dinv,
    unsigned short* __restrict__ csr, int n, int E, int nbuck) {
    __shared__ int cnt[256];
    __shared__ int wtot[4];
    __shared__ unsigned int stage[8192];
    int b = blockIdx.x;
    int t = threadIdx.x;
    int s = bstart[b];
    int e = bstart[b + 1];
    int m = e - s;
    cnt[t] = 0;
    __syncthreads();
    bool fits = (m <= 8192);
    for (int i = t; i < m; i += 256) {
        unsigned int v = part[s + i];
        if (fits) stage[i] = v;
        atomicAdd(&cnt[(v >> 16) & 255], 1);
    }
    __syncthreads();
    int c = cnt[t];
    int lane = t & 63, wv = t >> 6;
    int inc = c;
#pragma unroll
    for (int o = 1; o < 64; o <<= 1) {
        int u = __shfl_up(inc, o, 64);
        if (lane >= o) inc += u;
    }
    if (lane == 63) wtot[wv] = inc;
    __syncthreads();
    int wo = 0;
#pragma unroll
    for (int w2 = 0; w2 < 4; ++w2)
        if (w2 < wv) wo += wtot[w2];
    int excl = wo + inc - c;  // exclusive scan of cnt within bucket
    int d = (b << 8) + t;
    if (d < n) {
        rowptr[d] = s + excl;
        dinv[d] = rsqrtf((float)(c + 1));
    }
    if (b == nbuck - 1 && t == 255) rowptr[n] = E;
    __syncthreads();
    cnt[t] = excl;  // reuse as cursor
    __syncthreads();
    if (fits) {
        for (int i = t; i < m; i += 256) {
            unsigned int v = stage[i];
            int p = atomicAdd(&cnt[(v >> 16) & 255], 1);
            csr[s + p] = (unsigned short)(v & 0xFFFFu);
        }
    } else {
        for (int i = t; i < m; i += 256) {
            unsigned int v = part[s + i];
            int p = atomicAdd(&cnt[(v >> 16) & 255], 1);
            csr[s + p] = (unsigned short)(v & 0xFFFFu);
        }
    }
}

// ---------------- x (f32) -> xh (fp16) ----------------
__global__ __launch_bounds__(256) void tohalf_kernel(const float* __restrict__ x,
                                                     __half* __restrict__ xh, int nelem) {
    int i = blockIdx.x * blockDim.x + threadIdx.x;
    int base = i * 8;
    if (base >= nelem) return;
    float4 a = *(const float4*)&x[base];
    float4 b = *(const float4*)&x[base + 4];
    union { __half2 h[4]; uint4 u; } pk;
    pk.h[0] = __floats2half2_rn(a.x, a.y);
    pk.h[1] = __floats2half2_rn(a.z, a.w);
    pk.h[2] = __floats2half2_rn(b.x, b.y);
    pk.h[3] = __floats2half2_rn(b.z, b.w);
    *(uint4*)&xh[base] = pk.u;
}

// ---------------- MFMA GEMM: g = fp16((xh @ W) * dinv[row]) ----------------
// 256 thr = 4 waves, 64 rows x 128 cols per block. W^T staged in LDS as
// swizzled fp16 (32KB); epilogue transposes C via LDS (union region) for
// coalesced fp16 stores. mfma_f32_16x16x32_f16, frag layout per m89/m92:
//   a: lane l -> A[l&15][ks*32+(l>>4)*8 + 0..7] (16B contiguous)
//   b: lane l -> W^T[nt*16+(l&15)][same k range] (16B contiguous, XOR-swizzled)
//   d: lane l, reg r -> D[(l>>4)*4+r][l&15]
__global__ __launch_bounds__(256) void gemm_kernel(
    const __half* __restrict__ xh, const float* __restrict__ W,
    const float* __restrict__ dinv, __half* __restrict__ g, int n) {
    __shared__ union {
        unsigned short wt[F * F];  // [n][k^((n&7)<<3)] fp16, 32KB
        float cs[64 * 132];        // C staging, 33.8KB
    } sm;
    int t = threadIdx.x;

    // stage W^T fp16 swizzled: W is [k][n] f32
#pragma unroll
    for (int i = 0; i < 16; ++i) {
        int f = (i * 256 + t) * 4;  // 4 consecutive n, same k
        int k = f >> 7;
        int nn = f & 127;
        float4 w4 = *(const float4*)&W[f];
        sm.wt[(nn + 0) * F + (k ^ (((nn + 0) & 7) << 3))] = __half_as_ushort(__float2half_rn(w4.x));
        sm.wt[(nn + 1) * F + (k ^ (((nn + 1) & 7) << 3))] = __half_as_ushort(__float2half_rn(w4.y));
        sm.wt[(nn + 2) * F + (k ^ (((nn + 2) & 7) << 3))] = __half_as_ushort(__float2half_rn(w4.z));
        sm.wt[(nn + 3) * F + (k ^ (((nn + 3) & 7) << 3))] = __half_as_ushort(__float2half_rn(w4.w));
    }
    __syncthreads();

    int lane = t & 63;
    int wave = t >> 6;
    int r0 = blockIdx.x * 64;
    int arow = min(r0 + wave * 16 + (lane & 15), n - 1);
    int klane = (lane >> 4) * 8;
    const unsigned short* xp = (const unsigned short*)xh + (size_t)arow * F + klane;

    union FU { uintx4 u; half8 h; };
    FU af[4];
#pragma unroll
    for (int ks = 0; ks < 4; ++ks) af[ks].u = *(const uintx4*)(xp + ks * 32);

    int swz = (lane & 7) << 3;
    int colb = (lane & 15) * F;

    floatx4 acc[8];
#pragma unroll
    for (int nt = 0; nt < 8; ++nt) acc[nt] = (floatx4)(0.0f);

#pragma unroll
    for (int ks = 0; ks < 4; ++ks) {
        int k0 = ks * 32 + klane;
        int ko = k0 ^ swz;
#pragma unroll
        for (int nt = 0; nt < 8; ++nt) {
            FU bf;
            bf.u = *(const uintx4*)&sm.wt[nt * 16 * F + colb + ko];
            acc[nt] = __builtin_amdgcn_mfma_f32_16x16x32_f16(af[ks].h, bf.h, acc[nt], 0, 0, 0);
        }
    }

    __syncthreads();  // all waves done reading wt
    int crow = wave * 16 + (lane >> 4) * 4;
#pragma unroll
    for (int nt = 0; nt < 8; ++nt) {
        int ccol = nt * 16 + (lane & 15);
#pragma unroll
        for (int r = 0; r < 4; ++r) sm.cs[(crow + r) * 132 + ccol] = acc[nt][r];
    }
    __syncthreads();

#pragma unroll
    for (int i = 0; i < 16; ++i) {
        int f = i * 256 + t;
        int row = f >> 6;
        int cp = f & 63;
        int grow = r0 + row;
        if (grow < n) {
            float lo = sm.cs[row * 132 + cp * 2];
            float hi = sm.cs[row * 132 + cp * 2 + 1];
            float di = dinv[grow];
            ((__half2*)g)[(size_t)grow * 64 + cp] = __floats2half2_rn(lo * di, hi * di);
        }
    }
}

// ---------------- aggregate ----------------
// out[d] = [relu](dinv[d]*(sum_{s in N(d)} g[s] + g[d]) + b); fp16 in/out, f32 accum
template <bool RELU, bool OUT_HALF>
__global__ __launch_bounds__(256) void aggregate_kernel(
    const int* __restrict__ rowptr, const unsigned short* __restrict__ csr_src,
    const float* __restrict__ dinv, const __half* __restrict__ g,
    const float* __restrict__ bias, void* __restrict__ out, int n) {
    int lane = threadIdx.x & 63;
    int d = (blockIdx.x * blockDim.x + threadIdx.x) >> 6;
    if (d >= n) return;

    const __half2* gp = (const __half2*)g;  // [n][64]

    float2 f = __half22float2(gp[(size_t)d * 64 + lane]);  // self loop
    float accx = f.x, accy = f.y;

    int e = rowptr[d];
    int end = rowptr[d + 1];
    for (; e + 8 <= end; e += 8) {
        __half2 v[8];
#pragma unroll
        for (int j = 0; j < 8; ++j) {
            int s = csr_src[e + j];
            v[j] = gp[(size_t)s * 64 + lane];
        }
#pragma unroll
        for (int j = 0; j < 8; ++j) {
            float2 fv = __half22float2(v[j]);
            accx += fv.x;
            accy += fv.y;
        }
    }
    for (; e < end; ++e) {
        int s = csr_src[e];
        float2 fv = __half22float2(gp[(size_t)s * 64 + lane]);
        accx += fv.x;
        accy += fv.y;
    }

    float di = dinv[d];
    int c = lane * 2;
    float2 b = *(const float2*)&bias[c];
    float rx = di * accx + b.x;
    float ry = di * accy + b.y;
    if (RELU) {
        rx = fmaxf(rx, 0.0f);
        ry = fmaxf(ry, 0.0f);
    }
    if (OUT_HALF) {
        ((__half2*)out)[(size_t)d * 64 + lane] = __floats2half2_rn(rx, ry);
    } else {
        float2 r = {rx, ry};
        *(float2*)&((float*)out)[(size_t)d * F + c] = r;
    }
}

// ---------------- decode: out = sigmoid(dot(z[ls], z[ld])), z fp16 ----------------
__global__ __launch_bounds__(256) void decode_kernel(
    const int* __restrict__ ls, const int* __restrict__ ld,
    const __half* __restrict__ z, float* __restrict__ out, int EL) {
    int lane = threadIdx.x & 63;
    int w = (blockIdx.x * blockDim.x + threadIdx.x) >> 6;
    if (w >= EL) return;
    int a = ls[w];
    int b = ld[w];
    const __half2* zp = (const __half2*)z;
    float2 va = __half22float2(zp[(size_t)a * 64 + lane]);
    float2 vb = __half22float2(zp[(size_t)b * 64 + lane]);
    float s = va.x * vb.x + va.y * vb.y;
#pragma unroll
    for (int off = 32; off; off >>= 1) s += __shfl_xor(s, off, 64);
    if (lane == 0) out[w] = 1.0f / (1.0f + expf(-s));
}

extern "C" void kernel_launch(void* const* d_in, const int* in_sizes, int n_in,
                              void* d_out, int out_size, void* d_ws, size_t ws_size,
                              hipStream_t stream) {
    const float* x = (const float*)d_in[0];
    const int* ei = (const int*)d_in[1];
    const int* eli = (const int*)d_in[2];
    const float* W1 = (const float*)d_in[3];
    const float* b1 = (const float*)d_in[4];
    const float* W2 = (const float*)d_in[5];
    const float* b2 = (const float*)d_in[6];
    float* out = (float*)d_out;

    int E = in_sizes[1] / 2;
    int EL = in_sizes[2] / 2;
    const int* src = ei;
    const int* dst = ei + E;
    const int* ls = eli;
    const int* ld = eli + EL;
    int n = in_sizes[0] / F;     // 50000
    int nbuck = (n + 255) >> 8;  // 196

    char* ws = (char*)d_ws;
    float*          dinv      = (float*)(ws);                      // [0, 1MB)
    int*            rowptr    = (int*)(ws + (1u << 20));           // [1MB, 2MB)
    int*            blockhist = (int*)(ws + (2u << 20));           // [2MB, 2.5MB): NB*256 ints
    int*            bstart    = (int*)(ws + 2883584u);             // [2.75MB): 257 ints
    unsigned int*   part      = (unsigned int*)(ws + (3u << 20));  // [3MB, 6.2MB)
    unsigned short* csr       = (unsigned short*)(ws + 6815744u);  // [6.5MB, 8.1MB)
    __half*         xh        = (__half*)(ws + (9u << 20));        // [9MB, 21.8MB)
    __half*         gh        = (__half*)(ws + (22u << 20));       // [22MB, 34.8MB)
    __half*         z1h       = (__half*)(ws + (35u << 20));       // [35MB, 47.8MB)
    __half*         z2        = (__half*)(ws + (48u << 20));       // [48MB, 60.8MB)

    const int BS = 256;
    int gemm_blocks = (n + 63) / 64;
    int agg_blocks = (n + 3) / 4;
    int dec_blocks = (EL + 3) / 4;
    int cvt_blocks = (n * F / 8 + BS - 1) / BS;

    // ---- CSR build (radix partition by dst; emits rowptr + dinv) ----
    hist_kernel<<<NB, BS, 0, stream>>>(dst, blockhist, E);
    scanbuckets_kernel<<<1, BS, 0, stream>>>(blockhist, bstart, E);
    part_kernel<<<NB, BS, 0, stream>>>(src, dst, blockhist, part, E);
    bucket_kernel<<<nbuck, BS, 0, stream>>>(part, bstart, rowptr, dinv, csr, n, E, nbuck);

    // ---- x -> fp16 ----
    tohalf_kernel<<<cvt_blocks, BS, 0, stream>>>(x, xh, n * F);

    // ---- layer 1 ----
    gemm_kernel<<<gemm_blocks, BS, 0, stream>>>(xh, W1, dinv, gh, n);
    aggregate_kernel<true, true><<<agg_blocks, BS, 0, stream>>>(rowptr, csr, dinv, gh, b1, z1h, n);

    // ---- layer 2 ----
    gemm_kernel<<<gemm_blocks, BS, 0, stream>>>(z1h, W2, dinv, gh, n);
    aggregate_kernel<false, true><<<agg_blocks, BS, 0, stream>>>(rowptr, csr, dinv, gh, b2, z2, n);

    // ---- decode ----
    decode_kernel<<<dec_blocks, BS, 0, stream>>>(ls, ld, z2, out, EL);
}

// Round 9
// 221.745 us; speedup vs baseline: 11.9087x; 1.0758x over previous
//
#include <hip/hip_runtime.h>
#include <hip/hip_fp16.h>
#include <math.h>

#define NN 50000
#define F 128
#define NB 512  // partition blocks

typedef _Float16 half8 __attribute__((ext_vector_type(8)));
typedef float floatx4 __attribute__((ext_vector_type(4)));
typedef unsigned int uintx4 __attribute__((ext_vector_type(4)));

// ---------------- CSR build via 2-level radix partition by dst ----------------
// Pass 1: per-block LDS histogram of coarse bucket (dst>>8). blockhist[block][bucket].
__global__ __launch_bounds__(256) void hist_kernel(const int* __restrict__ dst,
                                                   int* __restrict__ blockhist, int E) {
    __shared__ int h[256];
    int t = threadIdx.x;
    h[t] = 0;
    __syncthreads();
    int chunk = (E + NB - 1) / NB;
    int s = blockIdx.x * chunk;
    int e = min(E, s + chunk);
    for (int i = s + t; i < e; i += 256) atomicAdd(&h[dst[i] >> 8], 1);
    __syncthreads();
    blockhist[blockIdx.x * 256 + t] = h[t];
}

// Pass 2 (1 block): bucket totals -> bucket_start; rewrite blockhist to offsets
__global__ __launch_bounds__(256) void scanbuckets_kernel(int* __restrict__ blockhist,
                                                          int* __restrict__ bstart, int E) {
    __shared__ int wtot[4];
    int t = threadIdx.x;
    int sum = 0;
#pragma unroll 8
    for (int j = 0; j < NB; ++j) sum += blockhist[j * 256 + t];
    int lane = t & 63, wv = t >> 6;
    int inc = sum;
#pragma unroll
    for (int o = 1; o < 64; o <<= 1) {
        int u = __shfl_up(inc, o, 64);
        if (lane >= o) inc += u;
    }
    if (lane == 63) wtot[wv] = inc;
    __syncthreads();
    int wo = 0;
#pragma unroll
    for (int w2 = 0; w2 < 4; ++w2)
        if (w2 < wv) wo += wtot[w2];
    int excl = wo + inc - sum;
    bstart[t] = excl;
    if (t == 255) bstart[256] = excl + sum;  // == E
    int run = excl;
#pragma unroll 4
    for (int j = 0; j < NB; ++j) {
        int v = blockhist[j * 256 + t];
        blockhist[j * 256 + t] = run;
        run += v;
    }
}

// Pass 3: scatter packed (dst&255)<<16 | src into bucket-contiguous ranges
__global__ __launch_bounds__(256) void part_kernel(const int* __restrict__ src,
                                                   const int* __restrict__ dst,
                                                   const int* __restrict__ blockhist,
                                                   unsigned int* __restrict__ part, int E) {
    __shared__ int cur[256];
    int t = threadIdx.x;
    cur[t] = blockhist[blockIdx.x * 256 + t];
    __syncthreads();
    int chunk = (E + NB - 1) / NB;
    int s = blockIdx.x * chunk;
    int e = min(E, s + chunk);
    for (int i = s + t; i < e; i += 256) {
        int dd = dst[i];
        int p = atomicAdd(&cur[dd >> 8], 1);
        part[p] = ((unsigned int)(dd & 255) << 16) | (unsigned int)src[i];
    }
}

// Pass 4: one block per coarse bucket: LDS counting sort by dst&255;
// emits csr (u16 src), rowptr and dinv for the bucket's 256 nodes.
__global__ __launch_bounds__(256) void bucket_kernel(
    const unsigned int* __restrict__ part, const int* __restrict__ bstart,
    int* __restrict__ rowptr, float* __restrict__ dinv,
    unsigned short* __restrict__ csr, int n, int E, int nbuck) {
    __shared__ int cnt[256];
    __shared__ int wtot[4];
    __shared__ unsigned int stage[8192];
    int b = blockIdx.x;
    int t = threadIdx.x;
    int s = bstart[b];
    int e = bstart[b + 1];
    int m = e - s;
    cnt[t] = 0;
    __syncthreads();
    bool fits = (m <= 8192);
    for (int i = t; i < m; i += 256) {
        unsigned int v = part[s + i];
        if (fits) stage[i] = v;
        atomicAdd(&cnt[(v >> 16) & 255], 1);
    }
    __syncthreads();
    int c = cnt[t];
    int lane = t & 63, wv = t >> 6;
    int inc = c;
#pragma unroll
    for (int o = 1; o < 64; o <<= 1) {
        int u = __shfl_up(inc, o, 64);
        if (lane >= o) inc += u;
    }
    if (lane == 63) wtot[wv] = inc;
    __syncthreads();
    int wo = 0;
#pragma unroll
    for (int w2 = 0; w2 < 4; ++w2)
        if (w2 < wv) wo += wtot[w2];
    int excl = wo + inc - c;  // exclusive scan of cnt within bucket
    int d = (b << 8) + t;
    if (d < n) {
        rowptr[d] = s + excl;
        dinv[d] = rsqrtf((float)(c + 1));
    }
    if (b == nbuck - 1 && t == 255) rowptr[n] = E;
    __syncthreads();
    cnt[t] = excl;  // reuse as cursor
    __syncthreads();
    if (fits) {
        for (int i = t; i < m; i += 256) {
            unsigned int v = stage[i];
            int p = atomicAdd(&cnt[(v >> 16) & 255], 1);
            csr[s + p] = (unsigned short)(v & 0xFFFFu);
        }
    } else {
        for (int i = t; i < m; i += 256) {
            unsigned int v = part[s + i];
            int p = atomicAdd(&cnt[(v >> 16) & 255], 1);
            csr[s + p] = (unsigned short)(v & 0xFFFFu);
        }
    }
}

// ---------------- MFMA GEMM: g = fp16((xin @ W) * dinv[row]) ----------------
// 256 thr = 4 waves, 64 rows x 128 cols per block. W^T staged in LDS as
// swizzled fp16 (32KB); epilogue transposes C via LDS (union region) for
// coalesced fp16 stores. mfma_f32_16x16x32_f16, frag layout per m89/m92:
//   a: lane l -> A[l&15][ks*32+(l>>4)*8 + 0..7]
//   b: lane l -> W^T[nt*16+(l&15)][same k range] (XOR-swizzled)
//   d: lane l, reg r -> D[(l>>4)*4+r][l&15]
// IN_F32: read f32 rows and convert in-register (fuses the tohalf pass).
template <bool IN_F32>
__global__ __launch_bounds__(256) void gemm_kernel(
    const void* __restrict__ xin, const float* __restrict__ W,
    const float* __restrict__ dinv, __half* __restrict__ g, int n) {
    __shared__ union {
        unsigned short wt[F * F];  // [n][k^((n&7)<<3)] fp16, 32KB
        float cs[64 * 132];        // C staging, 33.8KB
    } sm;
    int t = threadIdx.x;

    // stage W^T fp16 swizzled: W is [k][n] f32
#pragma unroll
    for (int i = 0; i < 16; ++i) {
        int f = (i * 256 + t) * 4;  // 4 consecutive n, same k
        int k = f >> 7;
        int nn = f & 127;
        float4 w4 = *(const float4*)&W[f];
        sm.wt[(nn + 0) * F + (k ^ (((nn + 0) & 7) << 3))] = __half_as_ushort(__float2half_rn(w4.x));
        sm.wt[(nn + 1) * F + (k ^ (((nn + 1) & 7) << 3))] = __half_as_ushort(__float2half_rn(w4.y));
        sm.wt[(nn + 2) * F + (k ^ (((nn + 2) & 7) << 3))] = __half_as_ushort(__float2half_rn(w4.z));
        sm.wt[(nn + 3) * F + (k ^ (((nn + 3) & 7) << 3))] = __half_as_ushort(__float2half_rn(w4.w));
    }
    __syncthreads();

    int lane = t & 63;
    int wave = t >> 6;
    int r0 = blockIdx.x * 64;
    int arow = min(r0 + wave * 16 + (lane & 15), n - 1);
    int klane = (lane >> 4) * 8;

    union FU { uintx4 u; half8 h; };
    FU af[4];
    if (IN_F32) {
        const float* xp = (const float*)xin + (size_t)arow * F + klane;
#pragma unroll
        for (int ks = 0; ks < 4; ++ks) {
            float4 a = *(const float4*)(xp + ks * 32);
            float4 b = *(const float4*)(xp + ks * 32 + 4);
            af[ks].h[0] = (_Float16)a.x; af[ks].h[1] = (_Float16)a.y;
            af[ks].h[2] = (_Float16)a.z; af[ks].h[3] = (_Float16)a.w;
            af[ks].h[4] = (_Float16)b.x; af[ks].h[5] = (_Float16)b.y;
            af[ks].h[6] = (_Float16)b.z; af[ks].h[7] = (_Float16)b.w;
        }
    } else {
        const unsigned short* xp = (const unsigned short*)xin + (size_t)arow * F + klane;
#pragma unroll
        for (int ks = 0; ks < 4; ++ks) af[ks].u = *(const uintx4*)(xp + ks * 32);
    }

    int swz = (lane & 7) << 3;
    int colb = (lane & 15) * F;

    floatx4 acc[8];
#pragma unroll
    for (int nt = 0; nt < 8; ++nt) acc[nt] = (floatx4)(0.0f);

#pragma unroll
    for (int ks = 0; ks < 4; ++ks) {
        int k0 = ks * 32 + klane;
        int ko = k0 ^ swz;
#pragma unroll
        for (int nt = 0; nt < 8; ++nt) {
            FU bf;
            bf.u = *(const uintx4*)&sm.wt[nt * 16 * F + colb + ko];
            acc[nt] = __builtin_amdgcn_mfma_f32_16x16x32_f16(af[ks].h, bf.h, acc[nt], 0, 0, 0);
        }
    }

    __syncthreads();  // all waves done reading wt
    int crow = wave * 16 + (lane >> 4) * 4;
#pragma unroll
    for (int nt = 0; nt < 8; ++nt) {
        int ccol = nt * 16 + (lane & 15);
#pragma unroll
        for (int r = 0; r < 4; ++r) sm.cs[(crow + r) * 132 + ccol] = acc[nt][r];
    }
    __syncthreads();

#pragma unroll
    for (int i = 0; i < 16; ++i) {
        int f = i * 256 + t;
        int row = f >> 6;
        int cp = f & 63;
        int grow = r0 + row;
        if (grow < n) {
            float lo = sm.cs[row * 132 + cp * 2];
            float hi = sm.cs[row * 132 + cp * 2 + 1];
            float di = dinv[grow];
            ((__half2*)g)[(size_t)grow * 64 + cp] = __floats2half2_rn(lo * di, hi * di);
        }
    }
}

// ---------------- aggregate ----------------
// out[d] = [relu](dinv[d]*(sum_{s in N(d)} g[s] + g[d]) + b); fp16 in/out, f32 accum
// 16-deep gather unroll for MLP in the latency/L3-bound random gather.
template <bool RELU, bool OUT_HALF>
__global__ __launch_bounds__(256) void aggregate_kernel(
    const int* __restrict__ rowptr, const unsigned short* __restrict__ csr_src,
    const float* __restrict__ dinv, const __half* __restrict__ g,
    const float* __restrict__ bias, void* __restrict__ out, int n) {
    int lane = threadIdx.x & 63;
    int d = (blockIdx.x * blockDim.x + threadIdx.x) >> 6;
    if (d >= n) return;

    const __half2* gp = (const __half2*)g;  // [n][64]

    float2 f = __half22float2(gp[(size_t)d * 64 + lane]);  // self loop
    float accx = f.x, accy = f.y;

    int e = rowptr[d];
    int end = rowptr[d + 1];
    for (; e + 16 <= end; e += 16) {
        __half2 v[16];
#pragma unroll
        for (int j = 0; j < 16; ++j) {
            int s = csr_src[e + j];
            v[j] = gp[(size_t)s * 64 + lane];
        }
#pragma unroll
        for (int j = 0; j < 16; ++j) {
            float2 fv = __half22float2(v[j]);
            accx += fv.x;
            accy += fv.y;
        }
    }
    for (; e + 4 <= end; e += 4) {
        __half2 v[4];
#pragma unroll
        for (int j = 0; j < 4; ++j) {
            int s = csr_src[e + j];
            v[j] = gp[(size_t)s * 64 + lane];
        }
#pragma unroll
        for (int j = 0; j < 4; ++j) {
            float2 fv = __half22float2(v[j]);
            accx += fv.x;
            accy += fv.y;
        }
    }
    for (; e < end; ++e) {
        int s = csr_src[e];
        float2 fv = __half22float2(gp[(size_t)s * 64 + lane]);
        accx += fv.x;
        accy += fv.y;
    }

    float di = dinv[d];
    int c = lane * 2;
    float2 b = *(const float2*)&bias[c];
    float rx = di * accx + b.x;
    float ry = di * accy + b.y;
    if (RELU) {
        rx = fmaxf(rx, 0.0f);
        ry = fmaxf(ry, 0.0f);
    }
    if (OUT_HALF) {
        ((__half2*)out)[(size_t)d * 64 + lane] = __floats2half2_rn(rx, ry);
    } else {
        float2 r = {rx, ry};
        *(float2*)&((float*)out)[(size_t)d * F + c] = r;
    }
}

// ---------------- decode: out = sigmoid(dot(z[ls], z[ld])), z fp16 ----------------
__global__ __launch_bounds__(256) void decode_kernel(
    const int* __restrict__ ls, const int* __restrict__ ld,
    const __half* __restrict__ z, float* __restrict__ out, int EL) {
    int lane = threadIdx.x & 63;
    int w = (blockIdx.x * blockDim.x + threadIdx.x) >> 6;
    if (w >= EL) return;
    int a = ls[w];
    int b = ld[w];
    const __half2* zp = (const __half2*)z;
    float2 va = __half22float2(zp[(size_t)a * 64 + lane]);
    float2 vb = __half22float2(zp[(size_t)b * 64 + lane]);
    float s = va.x * vb.x + va.y * vb.y;
#pragma unroll
    for (int off = 32; off; off >>= 1) s += __shfl_xor(s, off, 64);
    if (lane == 0) out[w] = 1.0f / (1.0f + expf(-s));
}

extern "C" void kernel_launch(void* const* d_in, const int* in_sizes, int n_in,
                              void* d_out, int out_size, void* d_ws, size_t ws_size,
                              hipStream_t stream) {
    const float* x = (const float*)d_in[0];
    const int* ei = (const int*)d_in[1];
    const int* eli = (const int*)d_in[2];
    const float* W1 = (const float*)d_in[3];
    const float* b1 = (const float*)d_in[4];
    const float* W2 = (const float*)d_in[5];
    const float* b2 = (const float*)d_in[6];
    float* out = (float*)d_out;

    int E = in_sizes[1] / 2;
    int EL = in_sizes[2] / 2;
    const int* src = ei;
    const int* dst = ei + E;
    const int* ls = eli;
    const int* ld = eli + EL;
    int n = in_sizes[0] / F;     // 50000
    int nbuck = (n + 255) >> 8;  // 196

    char* ws = (char*)d_ws;
    float*          dinv      = (float*)(ws);                      // [0, 1MB)
    int*            rowptr    = (int*)(ws + (1u << 20));           // [1MB, 2MB)
    int*            blockhist = (int*)(ws + (2u << 20));           // [2MB, 2.5MB): NB*256 ints
    int*            bstart    = (int*)(ws + 2883584u);             // [2.75MB): 257 ints
    unsigned int*   part      = (unsigned int*)(ws + (3u << 20));  // [3MB, 6.2MB)
    unsigned short* csr       = (unsigned short*)(ws + 6815744u);  // [6.5MB, 8.1MB)
    __half*         gh        = (__half*)(ws + (22u << 20));       // [22MB, 34.8MB)
    __half*         z1h       = (__half*)(ws + (35u << 20));       // [35MB, 47.8MB)
    __half*         z2        = (__half*)(ws + (48u << 20));       // [48MB, 60.8MB)

    const int BS = 256;
    int gemm_blocks = (n + 63) / 64;
    int agg_blocks = (n + 3) / 4;
    int dec_blocks = (EL + 3) / 4;

    // ---- CSR build (radix partition by dst; emits rowptr + dinv) ----
    hist_kernel<<<NB, BS, 0, stream>>>(dst, blockhist, E);
    scanbuckets_kernel<<<1, BS, 0, stream>>>(blockhist, bstart, E);
    part_kernel<<<NB, BS, 0, stream>>>(src, dst, blockhist, part, E);
    bucket_kernel<<<nbuck, BS, 0, stream>>>(part, bstart, rowptr, dinv, csr, n, E, nbuck);

    // ---- layer 1 (reads f32 x directly, converts in-register) ----
    gemm_kernel<true><<<gemm_blocks, BS, 0, stream>>>(x, W1, dinv, gh, n);
    aggregate_kernel<true, true><<<agg_blocks, BS, 0, stream>>>(rowptr, csr, dinv, gh, b1, z1h, n);

    // ---- layer 2 ----
    gemm_kernel<false><<<gemm_blocks, BS, 0, stream>>>(z1h, W2, dinv, gh, n);
    aggregate_kernel<false, true><<<agg_blocks, BS, 0, stream>>>(rowptr, csr, dinv, gh, b2, z2, n);

    // ---- decode ----
    decode_kernel<<<dec_blocks, BS, 0, stream>>>(ls, ld, z2, out, EL);
}

// Round 10
// 170.542 us; speedup vs baseline: 15.4840x; 1.3002x over previous
//
#include <hip/hip_runtime.h>
#include <hip/hip_fp16.h>
#include <math.h>

#define NN 50000
#define F 128
#define NB 512  // partition blocks

typedef _Float16 half8 __attribute__((ext_vector_type(8)));
typedef float floatx4 __attribute__((ext_vector_type(4)));
typedef unsigned int uintx4 __attribute__((ext_vector_type(4)));

// ---------------- CSR build via 2-level radix partition by dst ----------------
// Pass 1: per-block LDS histogram of coarse bucket (dst>>8). blockhist[block][bucket].
__global__ __launch_bounds__(256) void hist_kernel(const int* __restrict__ dst,
                                                   int* __restrict__ blockhist, int E) {
    __shared__ int h[256];
    int t = threadIdx.x;
    h[t] = 0;
    __syncthreads();
    int chunk = (E + NB - 1) / NB;
    int s = blockIdx.x * chunk;
    int e = min(E, s + chunk);
    for (int i = s + t; i < e; i += 256) atomicAdd(&h[dst[i] >> 8], 1);
    __syncthreads();
    blockhist[blockIdx.x * 256 + t] = h[t];
}

// Pass 2: 256 blocks, one per bucket: exclusive scan (over the 512 block
// entries) in-place; bucket total -> btot. Replaces the old single-block
// serial scanbuckets (2x512 serial iters on 1 CU).
__global__ __launch_bounds__(256) void scanA_kernel(int* __restrict__ blockhist,
                                                    int* __restrict__ btot) {
    __shared__ int wsum[4];
    int b = blockIdx.x;
    int t = threadIdx.x;
    int lane = t & 63, wv = t >> 6;
    int v0 = blockhist[t * 256 + b];
    int v1 = blockhist[(t + 256) * 256 + b];

    int inc = v0;
#pragma unroll
    for (int o = 1; o < 64; o <<= 1) {
        int u = __shfl_up(inc, o, 64);
        if (lane >= o) inc += u;
    }
    if (lane == 63) wsum[wv] = inc;
    __syncthreads();
    int woff = 0, tot0 = 0;
#pragma unroll
    for (int w2 = 0; w2 < 4; ++w2) {
        if (w2 < wv) woff += wsum[w2];
        tot0 += wsum[w2];
    }
    int p0 = woff + inc - v0;
    __syncthreads();  // done reading wsum

    int inc1 = v1;
#pragma unroll
    for (int o = 1; o < 64; o <<= 1) {
        int u = __shfl_up(inc1, o, 64);
        if (lane >= o) inc1 += u;
    }
    if (lane == 63) wsum[wv] = inc1;
    __syncthreads();
    int woff1 = 0, tot1 = 0;
#pragma unroll
    for (int w2 = 0; w2 < 4; ++w2) {
        if (w2 < wv) woff1 += wsum[w2];
        tot1 += wsum[w2];
    }
    int p1 = tot0 + woff1 + inc1 - v1;

    blockhist[t * 256 + b] = p0;
    blockhist[(t + 256) * 256 + b] = p1;
    if (t == 255) btot[b] = tot0 + tot1;
}

// Pass 3: scatter packed (dst&255)<<16 | src into bucket-contiguous ranges.
// Bucket bases are recomputed locally from btot (256-entry LDS scan, ~1us).
__global__ __launch_bounds__(256) void part_kernel(const int* __restrict__ src,
                                                   const int* __restrict__ dst,
                                                   const int* __restrict__ blockhist,
                                                   const int* __restrict__ btot,
                                                   unsigned int* __restrict__ part, int E) {
    __shared__ int cur[256];
    __shared__ int wsum[4];
    int t = threadIdx.x;
    int lane = t & 63, wv = t >> 6;
    int bt = btot[t];
    int inc = bt;
#pragma unroll
    for (int o = 1; o < 64; o <<= 1) {
        int u = __shfl_up(inc, o, 64);
        if (lane >= o) inc += u;
    }
    if (lane == 63) wsum[wv] = inc;
    __syncthreads();
    int woff = 0;
#pragma unroll
    for (int w2 = 0; w2 < 4; ++w2)
        if (w2 < wv) woff += wsum[w2];
    int bs = woff + inc - bt;  // exclusive bucket start
    cur[t] = blockhist[blockIdx.x * 256 + t] + bs;
    __syncthreads();

    int chunk = (E + NB - 1) / NB;
    int s = blockIdx.x * chunk;
    int e = min(E, s + chunk);
    for (int i = s + t; i < e; i += 256) {
        int dd = dst[i];
        int p = atomicAdd(&cur[dd >> 8], 1);
        part[p] = ((unsigned int)(dd & 255) << 16) | (unsigned int)src[i];
    }
}

// Pass 4: one block per coarse bucket: LDS counting sort by dst&255;
// emits csr (u16 src), rowptr and dinv for the bucket's 256 nodes.
__global__ __launch_bounds__(256) void bucket_kernel(
    const unsigned int* __restrict__ part, const int* __restrict__ btot,
    int* __restrict__ rowptr, float* __restrict__ dinv,
    unsigned short* __restrict__ csr, int n, int E, int nbuck) {
    __shared__ int cnt[256];
    __shared__ int wtot[4];
    __shared__ unsigned int stage[8192];
    __shared__ int sS, sM;
    int b = blockIdx.x;
    int t = threadIdx.x;
    int lane = t & 63, wv = t >> 6;

    // local exclusive scan of btot -> this bucket's [start, count]
    int bt = btot[t];
    int inc = bt;
#pragma unroll
    for (int o = 1; o < 64; o <<= 1) {
        int u = __shfl_up(inc, o, 64);
        if (lane >= o) inc += u;
    }
    if (lane == 63) wtot[wv] = inc;
    __syncthreads();
    int woff = 0;
#pragma unroll
    for (int w2 = 0; w2 < 4; ++w2)
        if (w2 < wv) woff += wtot[w2];
    int excl0 = woff + inc - bt;
    if (t == b) { sS = excl0; sM = bt; }
    cnt[t] = 0;
    __syncthreads();

    int s = sS;
    int m = sM;
    bool fits = (m <= 8192);
    for (int i = t; i < m; i += 256) {
        unsigned int v = part[s + i];
        if (fits) stage[i] = v;
        atomicAdd(&cnt[(v >> 16) & 255], 1);
    }
    __syncthreads();
    int c = cnt[t];
    int inc2 = c;
#pragma unroll
    for (int o = 1; o < 64; o <<= 1) {
        int u = __shfl_up(inc2, o, 64);
        if (lane >= o) inc2 += u;
    }
    if (lane == 63) wtot[wv] = inc2;
    __syncthreads();
    int wo = 0;
#pragma unroll
    for (int w2 = 0; w2 < 4; ++w2)
        if (w2 < wv) wo += wtot[w2];
    int excl = wo + inc2 - c;  // exclusive scan of cnt within bucket
    int d = (b << 8) + t;
    if (d < n) {
        rowptr[d] = s + excl;
        dinv[d] = rsqrtf((float)(c + 1));
    }
    if (b == nbuck - 1 && t == 255) rowptr[n] = E;
    __syncthreads();
    cnt[t] = excl;  // reuse as cursor
    __syncthreads();
    if (fits) {
        for (int i = t; i < m; i += 256) {
            unsigned int v = stage[i];
            int p = atomicAdd(&cnt[(v >> 16) & 255], 1);
            csr[s + p] = (unsigned short)(v & 0xFFFFu);
        }
    } else {
        for (int i = t; i < m; i += 256) {
            unsigned int v = part[s + i];
            int p = atomicAdd(&cnt[(v >> 16) & 255], 1);
            csr[s + p] = (unsigned short)(v & 0xFFFFu);
        }
    }
}

// ---------------- MFMA GEMM: g = fp16((xin @ W) * dinv[row]) ----------------
// 256 thr = 4 waves, 64 rows x 128 cols per block. W^T staged in LDS as
// swizzled fp16 (32KB); epilogue transposes C via LDS (union region) for
// coalesced fp16 stores. mfma_f32_16x16x32_f16, frag layout per m89/m92:
//   a: lane l -> A[l&15][ks*32+(l>>4)*8 + 0..7]
//   b: lane l -> W^T[nt*16+(l&15)][same k range] (XOR-swizzled)
//   d: lane l, reg r -> D[(l>>4)*4+r][l&15]
// IN_F32: read f32 rows and convert in-register (fuses the tohalf pass).
template <bool IN_F32>
__global__ __launch_bounds__(256) void gemm_kernel(
    const void* __restrict__ xin, const float* __restrict__ W,
    const float* __restrict__ dinv, __half* __restrict__ g, int n) {
    __shared__ union {
        unsigned short wt[F * F];  // [n][k^((n&7)<<3)] fp16, 32KB
        float cs[64 * 132];        // C staging, 33.8KB
    } sm;
    int t = threadIdx.x;

    // stage W^T fp16 swizzled: W is [k][n] f32
#pragma unroll
    for (int i = 0; i < 16; ++i) {
        int f = (i * 256 + t) * 4;  // 4 consecutive n, same k
        int k = f >> 7;
        int nn = f & 127;
        float4 w4 = *(const float4*)&W[f];
        sm.wt[(nn + 0) * F + (k ^ (((nn + 0) & 7) << 3))] = __half_as_ushort(__float2half_rn(w4.x));
        sm.wt[(nn + 1) * F + (k ^ (((nn + 1) & 7) << 3))] = __half_as_ushort(__float2half_rn(w4.y));
        sm.wt[(nn + 2) * F + (k ^ (((nn + 2) & 7) << 3))] = __half_as_ushort(__float2half_rn(w4.z));
        sm.wt[(nn + 3) * F + (k ^ (((nn + 3) & 7) << 3))] = __half_as_ushort(__float2half_rn(w4.w));
    }
    __syncthreads();

    int lane = t & 63;
    int wave = t >> 6;
    int r0 = blockIdx.x * 64;
    int arow = min(r0 + wave * 16 + (lane & 15), n - 1);
    int klane = (lane >> 4) * 8;

    union FU { uintx4 u; half8 h; };
    FU af[4];
    if (IN_F32) {
        const float* xp = (const float*)xin + (size_t)arow * F + klane;
#pragma unroll
        for (int ks = 0; ks < 4; ++ks) {
            float4 a = *(const float4*)(xp + ks * 32);
            float4 b = *(const float4*)(xp + ks * 32 + 4);
            af[ks].h[0] = (_Float16)a.x; af[ks].h[1] = (_Float16)a.y;
            af[ks].h[2] = (_Float16)a.z; af[ks].h[3] = (_Float16)a.w;
            af[ks].h[4] = (_Float16)b.x; af[ks].h[5] = (_Float16)b.y;
            af[ks].h[6] = (_Float16)b.z; af[ks].h[7] = (_Float16)b.w;
        }
    } else {
        const unsigned short* xp = (const unsigned short*)xin + (size_t)arow * F + klane;
#pragma unroll
        for (int ks = 0; ks < 4; ++ks) af[ks].u = *(const uintx4*)(xp + ks * 32);
    }

    int swz = (lane & 7) << 3;
    int colb = (lane & 15) * F;

    floatx4 acc[8];
#pragma unroll
    for (int nt = 0; nt < 8; ++nt) acc[nt] = (floatx4)(0.0f);

#pragma unroll
    for (int ks = 0; ks < 4; ++ks) {
        int k0 = ks * 32 + klane;
        int ko = k0 ^ swz;
#pragma unroll
        for (int nt = 0; nt < 8; ++nt) {
            FU bf;
            bf.u = *(const uintx4*)&sm.wt[nt * 16 * F + colb + ko];
            acc[nt] = __builtin_amdgcn_mfma_f32_16x16x32_f16(af[ks].h, bf.h, acc[nt], 0, 0, 0);
        }
    }

    __syncthreads();  // all waves done reading wt
    int crow = wave * 16 + (lane >> 4) * 4;
#pragma unroll
    for (int nt = 0; nt < 8; ++nt) {
        int ccol = nt * 16 + (lane & 15);
#pragma unroll
        for (int r = 0; r < 4; ++r) sm.cs[(crow + r) * 132 + ccol] = acc[nt][r];
    }
    __syncthreads();

#pragma unroll
    for (int i = 0; i < 16; ++i) {
        int f = i * 256 + t;
        int row = f >> 6;
        int cp = f & 63;
        int grow = r0 + row;
        if (grow < n) {
            float lo = sm.cs[row * 132 + cp * 2];
            float hi = sm.cs[row * 132 + cp * 2 + 1];
            float di = dinv[grow];
            ((__half2*)g)[(size_t)grow * 64 + cp] = __floats2half2_rn(lo * di, hi * di);
        }
    }
}

// ---------------- aggregate ----------------
// out[d] = [relu](dinv[d]*(sum_{s in N(d)} g[s] + g[d]) + b); fp16 in/out, f32 accum
// 16-deep gather unroll for MLP in the latency/L3-bound random gather.
template <bool RELU, bool OUT_HALF>
__global__ __launch_bounds__(256) void aggregate_kernel(
    const int* __restrict__ rowptr, const unsigned short* __restrict__ csr_src,
    const float* __restrict__ dinv, const __half* __restrict__ g,
    const float* __restrict__ bias, void* __restrict__ out, int n) {
    int lane = threadIdx.x & 63;
    int d = (blockIdx.x * blockDim.x + threadIdx.x) >> 6;
    if (d >= n) return;

    const __half2* gp = (const __half2*)g;  // [n][64]

    float2 f = __half22float2(gp[(size_t)d * 64 + lane]);  // self loop
    float accx = f.x, accy = f.y;

    int e = rowptr[d];
    int end = rowptr[d + 1];
    for (; e + 16 <= end; e += 16) {
        __half2 v[16];
#pragma unroll
        for (int j = 0; j < 16; ++j) {
            int s = csr_src[e + j];
            v[j] = gp[(size_t)s * 64 + lane];
        }
#pragma unroll
        for (int j = 0; j < 16; ++j) {
            float2 fv = __half22float2(v[j]);
            accx += fv.x;
            accy += fv.y;
        }
    }
    for (; e + 4 <= end; e += 4) {
        __half2 v[4];
#pragma unroll
        for (int j = 0; j < 4; ++j) {
            int s = csr_src[e + j];
            v[j] = gp[(size_t)s * 64 + lane];
        }
#pragma unroll
        for (int j = 0; j < 4; ++j) {
            float2 fv = __half22float2(v[j]);
            accx += fv.x;
            accy += fv.y;
        }
    }
    for (; e < end; ++e) {
        int s = csr_src[e];
        float2 fv = __half22float2(gp[(size_t)s * 64 + lane]);
        accx += fv.x;
        accy += fv.y;
    }

    float di = dinv[d];
    int c = lane * 2;
    float2 b = *(const float2*)&bias[c];
    float rx = di * accx + b.x;
    float ry = di * accy + b.y;
    if (RELU) {
        rx = fmaxf(rx, 0.0f);
        ry = fmaxf(ry, 0.0f);
    }
    if (OUT_HALF) {
        ((__half2*)out)[(size_t)d * 64 + lane] = __floats2half2_rn(rx, ry);
    } else {
        float2 r = {rx, ry};
        *(float2*)&((float*)out)[(size_t)d * F + c] = r;
    }
}

// ---------------- decode: out = sigmoid(dot(z[ls], z[ld])), z fp16 ----------------
// 4 edges per wave: 16 lanes/edge, 16B half8 loads, shfl-xor reduce width 16.
__global__ __launch_bounds__(256) void decode_kernel(
    const int* __restrict__ ls, const int* __restrict__ ld,
    const __half* __restrict__ z, float* __restrict__ out, int EL) {
    int t = threadIdx.x;
    int lane = t & 63;
    int grp = lane >> 4;
    int q = lane & 15;
    int wv = (blockIdx.x * blockDim.x + t) >> 6;
    int e = wv * 4 + grp;
    int ec = min(e, EL - 1);
    int a = ls[ec];
    int b = ld[ec];

    union FU { uintx4 u; __half2 h2[4]; };
    FU ua, ub;
    ua.u = *(const uintx4*)((const unsigned short*)z + (size_t)a * F + q * 8);
    ub.u = *(const uintx4*)((const unsigned short*)z + (size_t)b * F + q * 8);
    float s = 0.0f;
#pragma unroll
    for (int j = 0; j < 4; ++j) {
        float2 fa = __half22float2(ua.h2[j]);
        float2 fb = __half22float2(ub.h2[j]);
        s += fa.x * fb.x + fa.y * fb.y;
    }
#pragma unroll
    for (int off = 8; off; off >>= 1) s += __shfl_xor(s, off, 16);
    if (q == 0 && e < EL) out[e] = 1.0f / (1.0f + expf(-s));
}

extern "C" void kernel_launch(void* const* d_in, const int* in_sizes, int n_in,
                              void* d_out, int out_size, void* d_ws, size_t ws_size,
                              hipStream_t stream) {
    const float* x = (const float*)d_in[0];
    const int* ei = (const int*)d_in[1];
    const int* eli = (const int*)d_in[2];
    const float* W1 = (const float*)d_in[3];
    const float* b1 = (const float*)d_in[4];
    const float* W2 = (const float*)d_in[5];
    const float* b2 = (const float*)d_in[6];
    float* out = (float*)d_out;

    int E = in_sizes[1] / 2;
    int EL = in_sizes[2] / 2;
    const int* src = ei;
    const int* dst = ei + E;
    const int* ls = eli;
    const int* ld = eli + EL;
    int n = in_sizes[0] / F;     // 50000
    int nbuck = (n + 255) >> 8;  // 196

    char* ws = (char*)d_ws;
    float*          dinv      = (float*)(ws);                      // [0, 1MB)
    int*            rowptr    = (int*)(ws + (1u << 20));           // [1MB, 2MB)
    int*            blockhist = (int*)(ws + (2u << 20));           // [2MB, 2.5MB): NB*256 ints
    int*            btot      = (int*)(ws + 2883584u);             // [2.75MB): 256 ints
    unsigned int*   part      = (unsigned int*)(ws + (3u << 20));  // [3MB, 6.2MB)
    unsigned short* csr       = (unsigned short*)(ws + 6815744u);  // [6.5MB, 8.1MB)
    __half*         gh        = (__half*)(ws + (22u << 20));       // [22MB, 34.8MB)
    __half*         z1h       = (__half*)(ws + (35u << 20));       // [35MB, 47.8MB)
    __half*         z2        = (__half*)(ws + (48u << 20));       // [48MB, 60.8MB)

    const int BS = 256;
    int gemm_blocks = (n + 63) / 64;
    int agg_blocks = (n + 3) / 4;
    int dec_blocks = (EL + 15) / 16;

    // ---- CSR build (radix partition by dst; emits rowptr + dinv) ----
    hist_kernel<<<NB, BS, 0, stream>>>(dst, blockhist, E);
    scanA_kernel<<<256, BS, 0, stream>>>(blockhist, btot);
    part_kernel<<<NB, BS, 0, stream>>>(src, dst, blockhist, btot, part, E);
    bucket_kernel<<<nbuck, BS, 0, stream>>>(part, btot, rowptr, dinv, csr, n, E, nbuck);

    // ---- layer 1 (reads f32 x directly, converts in-register) ----
    gemm_kernel<true><<<gemm_blocks, BS, 0, stream>>>(x, W1, dinv, gh, n);
    aggregate_kernel<true, true><<<agg_blocks, BS, 0, stream>>>(rowptr, csr, dinv, gh, b1, z1h, n);

    // ---- layer 2 ----
    gemm_kernel<false><<<gemm_blocks, BS, 0, stream>>>(z1h, W2, dinv, gh, n);
    aggregate_kernel<false, true><<<agg_blocks, BS, 0, stream>>>(rowptr, csr, dinv, gh, b2, z2, n);

    // ---- decode ----
    decode_kernel<<<dec_blocks, BS, 0, stream>>>(ls, ld, z2, out, EL);
}